// Round 3
// baseline (828.025 us; speedup 1.0000x reference)
//
#include <hip/hip_runtime.h>
#include <hip/hip_bf16.h>
#include <cstdint>

#define B_   2
#define S_   2048
#define D_   4096
#define NH_  32
#define NKV_ 8
#define HD_  128
#define BS_  (B_*S_)      // 4096 rows
#define NQK_ 6144         // NH*HD + 2*NKV*HD

typedef __bf16 bf16_t;
typedef __bf16 bf16x8 __attribute__((ext_vector_type(8)));
typedef __bf16 bf16x4 __attribute__((ext_vector_type(4)));
typedef __bf16 bf16x2 __attribute__((ext_vector_type(2)));
typedef float  f32x4  __attribute__((ext_vector_type(4)));

typedef const __attribute__((address_space(1))) void* gas_ptr;
typedef __attribute__((address_space(3))) void* las_ptr;

__device__ __forceinline__ void gload_lds16(const void* g, void* l) {
  __builtin_amdgcn_global_load_lds((gas_ptr)g, (las_ptr)l, 16, 0, 0);
}

// ---------------- f32 -> bf16 convert (vectorized) ----------------
__global__ __launch_bounds__(256) void k_cvt(const float4* __restrict__ in,
                                             bf16x4* __restrict__ out, int n4) {
  int i = blockIdx.x * 256 + threadIdx.x;
  if (i >= n4) return;
  float4 v = in[i];
  bf16x4 o = { (bf16_t)v.x, (bf16_t)v.y, (bf16_t)v.z, (bf16_t)v.w };
  out[i] = o;
}

// ---------------- w[K][N] f32 -> wt[N][K] bf16 (tiled transpose) ----------------
__global__ __launch_bounds__(256) void k_transpose_cvt(const float* __restrict__ w,
                                                       bf16_t* __restrict__ wt,
                                                       int K, int N) {
  __shared__ float tile[32][33];
  int n0 = blockIdx.x * 32, k0 = blockIdx.y * 32;
  int tx = threadIdx.x, ty = threadIdx.y;   // 32x8
#pragma unroll
  for (int i = 0; i < 4; i++)
    tile[ty + 8*i][tx] = w[(size_t)(k0 + ty + 8*i) * N + n0 + tx];
  __syncthreads();
#pragma unroll
  for (int i = 0; i < 4; i++)
    wt[(size_t)(n0 + ty + 8*i) * K + k0 + tx] = (bf16_t)tile[tx][ty + 8*i];
}

// ---------------- 256x256 NT GEMM, counted-vmcnt quad-buffer pipeline ----------
// C[M][N] = A[M][K] @ Bt[N][K]^T. BK=32, 8 waves (2x4), per-wave 128x64.
// LDS: 4 buffers x (A 16KB + B 16KB) = 128 KB. Stage t+3 per tile; top-of-tile
// s_waitcnt vmcnt(8) + raw s_barrier (loads stay in flight across barriers, T4).
// Swizzle: byte col ^= (row&3)<<4, applied on global SOURCE for staging and on
// ds_read address (involution, rule #21) -> conflict-free b128 reads (T2).
template <typename CT>
__global__ __launch_bounds__(512, 2) void k_gemm256(const bf16_t* __restrict__ A,
                                                    const bf16_t* __restrict__ Bt,
                                                    CT* __restrict__ C,
                                                    int M, int N, int K) {
  __shared__ __align__(16) bf16_t As[4][256 * 32];
  __shared__ __align__(16) bf16_t Bs[4][256 * 32];
  const int tid = threadIdx.x;
  const int l = tid & 63, w = tid >> 6;
  const int lr = l & 15, lg = l >> 4;
  const int wm = w >> 2, wn = w & 3;       // 2 x 4 wave grid

  // XCD-aware bijective swizzle (nwg % 8 == 0 for all our launches)
  const int nwg = gridDim.x * gridDim.y;
  int bid = blockIdx.y * gridDim.x + blockIdx.x;
  bid = (bid & 7) * (nwg >> 3) + (bid >> 3);
  const int bm = bid / gridDim.x, bn = bid % gridDim.x;

  const bf16_t* Ab = A  + (size_t)bm * 256 * K;
  const bf16_t* Bb = Bt + (size_t)bn * 256 * K;

  // staging map: LDS byte o = (j*512+tid)*16 (linear dest); source col swizzled
  int srow[2], scol[2], sdst[2];
#pragma unroll
  for (int j = 0; j < 2; j++) {
    int o = (j * 512 + tid) * 16;
    int row = o >> 6, cb = o & 63;
    srow[j] = row;
    scol[j] = (cb ^ ((row & 3) << 4)) >> 1;
    sdst[j] = o >> 1;
  }

  // fragment read offsets (elements, within one tile buffer)
  int aoff[8], boff[4];
#pragma unroll
  for (int m = 0; m < 8; m++) {
    int r = wm * 128 + m * 16 + lr;
    aoff[m] = r * 32 + (((lg * 16) ^ ((r & 3) << 4)) >> 1);
  }
#pragma unroll
  for (int n = 0; n < 4; n++) {
    int r = wn * 64 + n * 16 + lr;
    boff[n] = r * 32 + (((lg * 16) ^ ((r & 3) << 4)) >> 1);
  }

  f32x4 acc[8][4];
#pragma unroll
  for (int m = 0; m < 8; m++)
#pragma unroll
    for (int n = 0; n < 4; n++) acc[m][n] = f32x4{0.f, 0.f, 0.f, 0.f};

  auto stage = [&](int t) {
    const int bu = t & 3;
    const int kt = t * 32;
#pragma unroll
    for (int j = 0; j < 2; j++)
      gload_lds16(Ab + (size_t)srow[j] * K + kt + scol[j], &As[bu][0] + sdst[j]);
#pragma unroll
    for (int j = 0; j < 2; j++)
      gload_lds16(Bb + (size_t)srow[j] * K + kt + scol[j], &Bs[bu][0] + sdst[j]);
  };

  const int NT = K >> 5;
  stage(0); stage(1); stage(2);

  for (int t = 0; t < NT; ++t) {
    if (t + 2 < NT)      asm volatile("s_waitcnt vmcnt(8)" ::: "memory");
    else if (t + 1 < NT) asm volatile("s_waitcnt vmcnt(4)" ::: "memory");
    else                 asm volatile("s_waitcnt vmcnt(0)" ::: "memory");
    __builtin_amdgcn_s_barrier();
    asm volatile("" ::: "memory");
    if (t + 3 < NT) stage(t + 3);

    const bf16_t* Ap = &As[t & 3][0];
    const bf16_t* Bp = &Bs[t & 3][0];
    bf16x8 bfr[4], af[4];
#pragma unroll
    for (int n = 0; n < 4; n++) bfr[n] = *(const bf16x8*)(Bp + boff[n]);
#pragma unroll
    for (int m = 0; m < 4; m++) af[m] = *(const bf16x8*)(Ap + aoff[m]);
    __builtin_amdgcn_s_setprio(1);
#pragma unroll
    for (int m = 0; m < 4; m++)
#pragma unroll
      for (int n = 0; n < 4; n++)
        acc[m][n] = __builtin_amdgcn_mfma_f32_16x16x32_bf16(af[m], bfr[n], acc[m][n], 0, 0, 0);
    __builtin_amdgcn_s_setprio(0);
#pragma unroll
    for (int m = 0; m < 4; m++) af[m] = *(const bf16x8*)(Ap + aoff[m + 4]);
    __builtin_amdgcn_s_setprio(1);
#pragma unroll
    for (int m = 0; m < 4; m++)
#pragma unroll
      for (int n = 0; n < 4; n++)
        acc[m + 4][n] = __builtin_amdgcn_mfma_f32_16x16x32_bf16(af[m], bfr[n], acc[m + 4][n], 0, 0, 0);
    __builtin_amdgcn_s_setprio(0);
    asm volatile("" ::: "memory");
  }

#pragma unroll
  for (int m = 0; m < 8; m++) {
    int row0 = bm * 256 + wm * 128 + m * 16 + lg * 4;
#pragma unroll
    for (int n = 0; n < 4; n++) {
      int col = bn * 256 + wn * 64 + n * 16 + lr;
#pragma unroll
      for (int i = 0; i < 4; i++)
        C[(size_t)(row0 + i) * N + col] = (CT)acc[m][n][i];
    }
  }
}

// ---------------- RoPE + head-major reorder ----------------
__global__ __launch_bounds__(256) void k_rope(const bf16_t* __restrict__ qkv,
                                              const float* __restrict__ fcos,
                                              const float* __restrict__ fsin,
                                              bf16_t* __restrict__ dst,
                                              int nheads, int col_off, float mul) {
  int idx = blockIdx.x * 256 + threadIdx.x;   // B*S*nheads*64 threads
  int p = idx & 63;
  int h = (idx >> 6) % nheads;
  int bs = idx / (64 * nheads);
  int s = bs & (S_ - 1);
  int b = bs >> 11;                            // bs / S_
  const bf16_t* src = qkv + (size_t)bs * NQK_ + col_off + h * HD_ + 2 * p;
  bf16x2 ab = *(const bf16x2*)src;
  float a = (float)ab[0], bb = (float)ab[1];
  float c = fcos[s * 64 + p], sn = fsin[s * 64 + p];
  bf16x2 o = { (bf16_t)((a * c - bb * sn) * mul), (bf16_t)((a * sn + bb * c) * mul) };
  *(bf16x2*)(dst + ((((size_t)b * nheads + h) * S_ + s) * HD_) + 2 * p) = o;
}

// ---------------- V transpose: qkv v-cols -> vt[B][NKV][HD][S] ----------------
__global__ __launch_bounds__(256) void k_vtrans(const bf16_t* __restrict__ qkv,
                                                bf16_t* __restrict__ vtr) {
  __shared__ bf16_t tile[32][33];
  int s0 = blockIdx.x * 32, d0 = blockIdx.y * 32, z = blockIdx.z;  // z = b*NKV+kvh
  int b = z >> 3, kvh = z & 7;
  int tx = threadIdx.x, ty = threadIdx.y;
#pragma unroll
  for (int i = 0; i < 4; i++)
    tile[ty + 8*i][tx] =
        qkv[(size_t)(b * S_ + s0 + ty + 8*i) * NQK_ + (D_ + NKV_ * HD_) + kvh * HD_ + d0 + tx];
  __syncthreads();
#pragma unroll
  for (int i = 0; i < 4; i++)
    vtr[((size_t)z * HD_ + d0 + ty + 8*i) * S_ + s0 + tx] = tile[tx][ty + 8*i];
}

// ---------------- Flash attention (non-causal, GQA) ----------------
// grid (S/128, NH, B), 256 thr (4 waves). Wave w owns q rows [qb*128+w*32, +32)
// as two 16-row m-frags. K/V tiles (KVBLK=64) staged in LDS, double-buffered,
// XOR-swizzled (pre-swizzled global source, linear LDS dest per m173/rule21).
#define KVBLK 64
__global__ __launch_bounds__(256, 2) void k_flash(const bf16_t* __restrict__ qr,
                                                  const bf16_t* __restrict__ kr,
                                                  const bf16_t* __restrict__ vt,
                                                  bf16_t* __restrict__ ctx) {
  __shared__ __align__(16) bf16_t Ks[2][KVBLK * HD_];   // 2 x 16 KB [row s][col d]
  __shared__ __align__(16) bf16_t Vs[2][HD_ * KVBLK];   // 2 x 16 KB [row d][col s]
  __shared__ __align__(16) bf16_t plds[4][16][72];      // per-wave P scratch
  const int tid = threadIdx.x;
  const int l = tid & 63, w = tid >> 6;
  const int lr = l & 15, lg = l >> 4;
  const int qb = blockIdx.x, h = blockIdx.y, b = blockIdx.z;
  const int kvh = h >> 2;   // NREP=4

  const bf16_t* qbase = qr + (((size_t)b * NH_ + h) * S_ + qb * 128 + w * 32) * HD_;
  const bf16_t* kbase = kr + (((size_t)b * NKV_ + kvh) * S_) * HD_;
  const bf16_t* vbase = vt + (((size_t)b * NKV_ + kvh) * HD_) * S_;

  // Q fragments (pre-scaled by 1/sqrt(HD) in k_rope)
  bf16x8 qf[2][4];
#pragma unroll
  for (int m = 0; m < 2; m++)
#pragma unroll
    for (int kk = 0; kk < 4; kk++)
      qf[m][kk] = *(const bf16x8*)(qbase + (m * 16 + lr) * HD_ + kk * 32 + lg * 8);

  f32x4 o[2][8];
#pragma unroll
  for (int m = 0; m < 2; m++)
#pragma unroll
    for (int n = 0; n < 8; n++) o[m][n] = f32x4{0.f, 0.f, 0.f, 0.f};
  float mR[2][4], lR[2][4];
#pragma unroll
  for (int m = 0; m < 2; m++)
#pragma unroll
    for (int i = 0; i < 4; i++) { mR[m][i] = -1e30f; lR[m][i] = 0.f; }

  // stage tile t into buffer bu (K: 16KB, V: 16KB; 8 gload16/thread)
  auto stage = [&](int bu, int t) {
    const int kb = t * KVBLK;
#pragma unroll
    for (int j = 0; j < 4; j++) {
      int o_ = (tid + 256 * j) * 16;                 // byte offset in K tile
      int row = o_ >> 8, cb = o_ & 255;              // row stride 256B
      int scb = cb ^ ((row & 7) << 4);
      gload_lds16(kbase + (size_t)(kb + row) * HD_ + (scb >> 1),
                  &Ks[bu][0] + (o_ >> 1));
    }
#pragma unroll
    for (int j = 0; j < 4; j++) {
      int o_ = (tid + 256 * j) * 16;                 // byte offset in V tile
      int row = o_ >> 7, cb = o_ & 127;              // row stride 128B
      int scb = cb ^ ((row & 7) << 4);
      gload_lds16(vbase + (size_t)row * S_ + kb + (scb >> 1),
                  &Vs[bu][0] + (o_ >> 1));
    }
  };

  const int nt = S_ / KVBLK;
  stage(0, 0);
  __syncthreads();
  int buf = 0;

  for (int t = 0; t < nt; t++) {
    if (t + 1 < nt) stage(buf ^ 1, t + 1);
    const bf16_t* Kb = &Ks[buf][0];
    const bf16_t* Vb = &Vs[buf][0];

    // QK^T: sc[m][n], K frag shared across m
    f32x4 sc[2][4];
#pragma unroll
    for (int m = 0; m < 2; m++)
#pragma unroll
      for (int n = 0; n < 4; n++) sc[m][n] = f32x4{0.f, 0.f, 0.f, 0.f};
#pragma unroll
    for (int n = 0; n < 4; n++) {
#pragma unroll
      for (int kk = 0; kk < 4; kk++) {
        int r = n * 16 + lr;
        int cb = (kk * 64 + lg * 16) ^ ((r & 7) << 4);
        bf16x8 kf = *(const bf16x8*)(Kb + (((r << 8) + cb) >> 1));
        sc[0][n] = __builtin_amdgcn_mfma_f32_16x16x32_bf16(qf[0][kk], kf, sc[0][n], 0, 0, 0);
        sc[1][n] = __builtin_amdgcn_mfma_f32_16x16x32_bf16(qf[1][kk], kf, sc[1][n], 0, 0, 0);
      }
    }

    // online softmax per m-frag; P staged via per-wave LDS, read back to regs
    bf16x8 pf[2][2];
#pragma unroll
    for (int m = 0; m < 2; m++) {
      float alpha[4], psum[4];
#pragma unroll
      for (int i = 0; i < 4; i++) {
        float tmx = fmaxf(fmaxf(sc[m][0][i], sc[m][1][i]),
                          fmaxf(sc[m][2][i], sc[m][3][i]));
        tmx = fmaxf(tmx, __shfl_xor(tmx, 1));
        tmx = fmaxf(tmx, __shfl_xor(tmx, 2));
        tmx = fmaxf(tmx, __shfl_xor(tmx, 4));
        tmx = fmaxf(tmx, __shfl_xor(tmx, 8));
        float mnew = fmaxf(mR[m][i], tmx);
        alpha[i] = __expf(mR[m][i] - mnew);
        mR[m][i] = mnew;
        psum[i] = 0.f;
      }
#pragma unroll
      for (int n = 0; n < 4; n++)
#pragma unroll
        for (int i = 0; i < 4; i++) {
          float pv = __expf(sc[m][n][i] - mR[m][i]);
          psum[i] += pv;
          plds[w][lg * 4 + i][n * 16 + lr] = (bf16_t)pv;
        }
#pragma unroll
      for (int i = 0; i < 4; i++) {
        float t2 = psum[i];
        t2 += __shfl_xor(t2, 1);
        t2 += __shfl_xor(t2, 2);
        t2 += __shfl_xor(t2, 4);
        t2 += __shfl_xor(t2, 8);
        lR[m][i] = lR[m][i] * alpha[i] + t2;
      }
#pragma unroll
      for (int n = 0; n < 8; n++)
#pragma unroll
        for (int i = 0; i < 4; i++) o[m][n][i] *= alpha[i];
      pf[m][0] = *(const bf16x8*)(&plds[w][lr][lg * 8]);
      pf[m][1] = *(const bf16x8*)(&plds[w][lr][32 + lg * 8]);
    }

    // PV: V frag loaded once, shared across both m
#pragma unroll
    for (int n = 0; n < 8; n++) {
#pragma unroll
      for (int kk = 0; kk < 2; kk++) {
        int r = n * 16 + lr;
        int cb = (kk * 64 + lg * 16) ^ ((r & 7) << 4);
        bf16x8 vf = *(const bf16x8*)(Vb + (((r << 7) + cb) >> 1));
        o[0][n] = __builtin_amdgcn_mfma_f32_16x16x32_bf16(pf[0][kk], vf, o[0][n], 0, 0, 0);
        o[1][n] = __builtin_amdgcn_mfma_f32_16x16x32_bf16(pf[1][kk], vf, o[1][n], 0, 0, 0);
      }
    }
    __syncthreads();
    buf ^= 1;
  }

#pragma unroll
  for (int m = 0; m < 2; m++)
#pragma unroll
    for (int n = 0; n < 8; n++)
#pragma unroll
      for (int i = 0; i < 4; i++) {
        int srow = qb * 128 + w * 32 + m * 16 + lg * 4 + i;
        int d = n * 16 + lr;
        ctx[((size_t)(b * S_ + srow)) * D_ + h * HD_ + d] = (bf16_t)(o[m][n][i] / lR[m][i]);
      }
}

// ---------------- launch ----------------
extern "C" void kernel_launch(void* const* d_in, const int* in_sizes, int n_in,
                              void* d_out, int out_size, void* d_ws, size_t ws_size,
                              hipStream_t stream) {
  const float* x    = (const float*)d_in[0];
  const float* wq   = (const float*)d_in[1];
  const float* wk   = (const float*)d_in[2];
  const float* wv   = (const float*)d_in[3];
  const float* wo   = (const float*)d_in[4];
  const float* fcos = (const float*)d_in[5];
  const float* fsin = (const float*)d_in[6];
  float* out = (float*)d_out;

  // workspace layout (aliased; 160 MB total)
  const size_t SZ_XB    = (size_t)BS_ * D_ * 2;      // 32 MB  (xb, later qrope)
  const size_t SZ_WQKVT = (size_t)NQK_ * D_ * 2;     // 48 MB  (wqkvt, later krope+vtr)
  const size_t SZ_WOT   = (size_t)D_ * D_ * 2;       // 32 MB
  char* p = (char*)d_ws;
  bf16_t* xb    = (bf16_t*)p;                        // then qrope
  bf16_t* wqkvt = (bf16_t*)(p + SZ_XB);              // then krope, vtr
  bf16_t* wot   = (bf16_t*)(p + SZ_XB + SZ_WQKVT);
  bf16_t* qkv   = (bf16_t*)(p + SZ_XB + SZ_WQKVT + SZ_WOT);  // then ctx
  bf16_t* qrope = xb;
  bf16_t* krope = wqkvt;
  bf16_t* vtr   = wqkvt + (size_t)BS_ * NKV_ * HD_;
  bf16_t* ctx   = qkv;

  dim3 tb(32, 8);
  // 1. x -> bf16
  k_cvt<<<BS_ * D_ / 1024, 256, 0, stream>>>((const float4*)x, (bf16x4*)xb, BS_ * D_ / 4);
  // 2. transpose+convert weights (fused qkv weight, then wo)
  k_transpose_cvt<<<dim3(D_ / 32, D_ / 32), tb, 0, stream>>>(wq, wqkvt, D_, D_);
  k_transpose_cvt<<<dim3(32, D_ / 32), tb, 0, stream>>>(wk, wqkvt + (size_t)D_ * D_, D_, NKV_ * HD_);
  k_transpose_cvt<<<dim3(32, D_ / 32), tb, 0, stream>>>(wv, wqkvt + (size_t)(D_ + NKV_ * HD_) * D_, D_, NKV_ * HD_);
  k_transpose_cvt<<<dim3(D_ / 32, D_ / 32), tb, 0, stream>>>(wo, wot, D_, D_);
  // 3. fused QKV projection (256^2 pipeline; grid 24x16=384 blocks, %8==0)
  k_gemm256<bf16_t><<<dim3(NQK_ / 256, BS_ / 256), 512, 0, stream>>>(xb, wqkvt, qkv, BS_, NQK_, D_);
  // 4. RoPE + reorder (Q pre-scaled by 1/sqrt(HD)), V transpose
  k_rope<<<BS_ * NH_ * 64 / 256, 256, 0, stream>>>(qkv, fcos, fsin, qrope, NH_, 0, 0.08838834764831845f);
  k_rope<<<BS_ * NKV_ * 64 / 256, 256, 0, stream>>>(qkv, fcos, fsin, krope, NKV_, D_, 1.0f);
  k_vtrans<<<dim3(S_ / 32, HD_ / 32, B_ * NKV_), tb, 0, stream>>>(qkv, vtr);
  // 5. flash attention
  k_flash<<<dim3(S_ / 128, NH_, B_), 256, 0, stream>>>(qrope, krope, vtr, ctx);
  // 6. output projection -> f32 out (grid 16x16=256 blocks)
  k_gemm256<float><<<dim3(D_ / 256, BS_ / 256), 512, 0, stream>>>(ctx, wot, out, BS_, D_, D_);
}

// Round 4
// 805.556 us; speedup vs baseline: 1.0279x; 1.0279x over previous
//
#include <hip/hip_runtime.h>
#include <hip/hip_bf16.h>
#include <cstdint>

#define B_   2
#define S_   2048
#define D_   4096
#define NH_  32
#define NKV_ 8
#define HD_  128
#define BS_  (B_*S_)      // 4096 rows
#define NQK_ 6144         // NH*HD + 2*NKV*HD

typedef __bf16 bf16_t;
typedef __bf16 bf16x8 __attribute__((ext_vector_type(8)));
typedef __bf16 bf16x4 __attribute__((ext_vector_type(4)));
typedef __bf16 bf16x2 __attribute__((ext_vector_type(2)));
typedef float  f32x4  __attribute__((ext_vector_type(4)));

typedef const __attribute__((address_space(1))) void* gas_ptr;
typedef __attribute__((address_space(3))) void* las_ptr;

__device__ __forceinline__ void gload_lds16(const void* g, void* l) {
  __builtin_amdgcn_global_load_lds((gas_ptr)g, (las_ptr)l, 16, 0, 0);
}

#define LD8(p) (*(const bf16x8*)(p))

// ---------------- f32 -> bf16 convert (vectorized) ----------------
__global__ __launch_bounds__(256) void k_cvt(const float4* __restrict__ in,
                                             bf16x4* __restrict__ out, int n4) {
  int i = blockIdx.x * 256 + threadIdx.x;
  if (i >= n4) return;
  float4 v = in[i];
  bf16x4 o = { (bf16_t)v.x, (bf16_t)v.y, (bf16_t)v.z, (bf16_t)v.w };
  out[i] = o;
}

// ---------------- w[K][N] f32 -> wt[N][K] bf16 (tiled transpose) ----------------
__global__ __launch_bounds__(256) void k_transpose_cvt(const float* __restrict__ w,
                                                       bf16_t* __restrict__ wt,
                                                       int K, int N) {
  __shared__ float tile[32][33];
  int n0 = blockIdx.x * 32, k0 = blockIdx.y * 32;
  int tx = threadIdx.x, ty = threadIdx.y;   // 32x8
#pragma unroll
  for (int i = 0; i < 4; i++)
    tile[ty + 8*i][tx] = w[(size_t)(k0 + ty + 8*i) * N + n0 + tx];
  __syncthreads();
#pragma unroll
  for (int i = 0; i < 4; i++)
    wt[(size_t)(n0 + ty + 8*i) * K + k0 + tx] = (bf16_t)tile[tx][ty + 8*i];
}

// ---------------- 256x128 NT GEMM, 4-phase interleave, triple-buffer, counted vmcnt
// C[M][N] = A[M][K] @ Bt[N][K]^T. BK=64, 8 waves (4m x 2n), per-wave 64x64.
// LDS: 3 bufs x (A 32KB + B 16KB) = 144 KB. Tile t in buf t%3; during tile t's
// phases we stage tile t+2 into buf (t+2)%3 (its last reader, tile t-1, finished
// before tile t's phase-0 barrier -> race-free; per-phase barriers bound skew).
// Boundary wait: vmcnt(6) = tile t+1's 6 loads stay in flight (T4, never drain).
// Swizzle: byte ^= (row&7)<<4 within 128B rows, both-sides (pre-swizzled global
// source + swizzled ds_read) -> 8-way spread, 2 lanes/16B slot = free.
template <typename CT>
__global__ __launch_bounds__(512, 2) void k_gemm256(const bf16_t* __restrict__ A,
                                                    const bf16_t* __restrict__ Bt,
                                                    CT* __restrict__ C,
                                                    int M, int N, int K) {
  __shared__ __align__(16) bf16_t As[3][256 * 64];   // 3 x 32 KB
  __shared__ __align__(16) bf16_t Bs[3][128 * 64];   // 3 x 16 KB
  const int tid = threadIdx.x;
  const int l = tid & 63, w = tid >> 6;
  const int lr = l & 15, lg = l >> 4;
  const int wm = w >> 1, wn = w & 1;       // 4 x 2 wave grid

  // XCD-aware chunked swizzle (nwg % 8 == 0 for all our launches)
  const int nwg = gridDim.x * gridDim.y;
  int bid = blockIdx.y * gridDim.x + blockIdx.x;
  bid = (bid & 7) * (nwg >> 3) + (bid >> 3);
  const int bm = bid / gridDim.x, bn = bid % gridDim.x;

  const bf16_t* Ab = A  + (size_t)bm * 256 * K;
  const bf16_t* Bb = Bt + (size_t)bn * 128 * K;

  // staging maps: linear LDS dest byte o; global source col pre-swizzled
  int sa_row[4], sa_col[4], sa_dst[4];
#pragma unroll
  for (int j = 0; j < 4; j++) {
    int o = (j * 512 + tid) * 16;
    int row = o >> 7, cb = o & 127;
    sa_row[j] = row;
    sa_col[j] = (cb ^ ((row & 7) << 4)) >> 1;
    sa_dst[j] = o >> 1;
  }
  int sb_row[2], sb_col[2], sb_dst[2];
#pragma unroll
  for (int j = 0; j < 2; j++) {
    int o = (j * 512 + tid) * 16;
    int row = o >> 7, cb = o & 127;
    sb_row[j] = row;
    sb_col[j] = (cb ^ ((row & 7) << 4)) >> 1;
    sb_dst[j] = o >> 1;
  }

  // fragment read offsets (elements, within one buffer; row = 64 elems = 128B)
  int aoff[4][2], boff[4][2];
#pragma unroll
  for (int m = 0; m < 4; m++)
#pragma unroll
    for (int kk = 0; kk < 2; kk++) {
      int r = wm * 64 + m * 16 + lr;
      aoff[m][kk] = r * 64 + (((kk * 64 + lg * 16) ^ ((r & 7) << 4)) >> 1);
    }
#pragma unroll
  for (int n = 0; n < 4; n++)
#pragma unroll
    for (int kk = 0; kk < 2; kk++) {
      int r = wn * 64 + n * 16 + lr;
      boff[n][kk] = r * 64 + (((kk * 64 + lg * 16) ^ ((r & 7) << 4)) >> 1);
    }

  f32x4 acc[4][4];
#pragma unroll
  for (int m = 0; m < 4; m++)
#pragma unroll
    for (int n = 0; n < 4; n++) acc[m][n] = f32x4{0.f, 0.f, 0.f, 0.f};

  const int NT = K >> 6;

  // prologue: stage tiles 0 and 1 fully (6 loads each, same per-wave order)
#pragma unroll
  for (int t = 0; t < 2; t++) {
    const int kt = t * 64;
#pragma unroll
    for (int j = 0; j < 4; j++)
      gload_lds16(Ab + (size_t)sa_row[j] * K + kt + sa_col[j], &As[t][0] + sa_dst[j]);
#pragma unroll
    for (int j = 0; j < 2; j++)
      gload_lds16(Bb + (size_t)sb_row[j] * K + kt + sb_col[j], &Bs[t][0] + sb_dst[j]);
  }

  int bu = 0, st = 2;
  for (int t = 0; t < NT; ++t) {
    const bf16_t* Ap = &As[bu][0];
    const bf16_t* Bp = &Bs[bu][0];
    const bool stg = (t + 2 < NT);
    const int kt2 = (t + 2) << 6;
    bf16x8 bf0, bf1, bf2, bf3, a0, a1;

    // ---- phase 0: kk0, m0/m1 ----
    if (t + 1 < NT) asm volatile("s_waitcnt vmcnt(6)" ::: "memory");
    else            asm volatile("s_waitcnt vmcnt(0)" ::: "memory");
    __builtin_amdgcn_s_barrier();
    bf0 = LD8(Bp + boff[0][0]); bf1 = LD8(Bp + boff[1][0]);
    bf2 = LD8(Bp + boff[2][0]); bf3 = LD8(Bp + boff[3][0]);
    a0 = LD8(Ap + aoff[0][0]);  a1 = LD8(Ap + aoff[1][0]);
    if (stg) {
      gload_lds16(Ab + (size_t)sa_row[0] * K + kt2 + sa_col[0], &As[st][0] + sa_dst[0]);
      gload_lds16(Ab + (size_t)sa_row[1] * K + kt2 + sa_col[1], &As[st][0] + sa_dst[1]);
    }
    __builtin_amdgcn_s_setprio(1);
    acc[0][0] = __builtin_amdgcn_mfma_f32_16x16x32_bf16(a0, bf0, acc[0][0], 0, 0, 0);
    acc[0][1] = __builtin_amdgcn_mfma_f32_16x16x32_bf16(a0, bf1, acc[0][1], 0, 0, 0);
    acc[0][2] = __builtin_amdgcn_mfma_f32_16x16x32_bf16(a0, bf2, acc[0][2], 0, 0, 0);
    acc[0][3] = __builtin_amdgcn_mfma_f32_16x16x32_bf16(a0, bf3, acc[0][3], 0, 0, 0);
    acc[1][0] = __builtin_amdgcn_mfma_f32_16x16x32_bf16(a1, bf0, acc[1][0], 0, 0, 0);
    acc[1][1] = __builtin_amdgcn_mfma_f32_16x16x32_bf16(a1, bf1, acc[1][1], 0, 0, 0);
    acc[1][2] = __builtin_amdgcn_mfma_f32_16x16x32_bf16(a1, bf2, acc[1][2], 0, 0, 0);
    acc[1][3] = __builtin_amdgcn_mfma_f32_16x16x32_bf16(a1, bf3, acc[1][3], 0, 0, 0);
    __builtin_amdgcn_s_setprio(0);

    // ---- phase 1: kk0, m2/m3 ----
    __builtin_amdgcn_s_barrier();
    a0 = LD8(Ap + aoff[2][0]);  a1 = LD8(Ap + aoff[3][0]);
    if (stg) {
      gload_lds16(Ab + (size_t)sa_row[2] * K + kt2 + sa_col[2], &As[st][0] + sa_dst[2]);
      gload_lds16(Ab + (size_t)sa_row[3] * K + kt2 + sa_col[3], &As[st][0] + sa_dst[3]);
    }
    __builtin_amdgcn_s_setprio(1);
    acc[2][0] = __builtin_amdgcn_mfma_f32_16x16x32_bf16(a0, bf0, acc[2][0], 0, 0, 0);
    acc[2][1] = __builtin_amdgcn_mfma_f32_16x16x32_bf16(a0, bf1, acc[2][1], 0, 0, 0);
    acc[2][2] = __builtin_amdgcn_mfma_f32_16x16x32_bf16(a0, bf2, acc[2][2], 0, 0, 0);
    acc[2][3] = __builtin_amdgcn_mfma_f32_16x16x32_bf16(a0, bf3, acc[2][3], 0, 0, 0);
    acc[3][0] = __builtin_amdgcn_mfma_f32_16x16x32_bf16(a1, bf0, acc[3][0], 0, 0, 0);
    acc[3][1] = __builtin_amdgcn_mfma_f32_16x16x32_bf16(a1, bf1, acc[3][1], 0, 0, 0);
    acc[3][2] = __builtin_amdgcn_mfma_f32_16x16x32_bf16(a1, bf2, acc[3][2], 0, 0, 0);
    acc[3][3] = __builtin_amdgcn_mfma_f32_16x16x32_bf16(a1, bf3, acc[3][3], 0, 0, 0);
    __builtin_amdgcn_s_setprio(0);

    // ---- phase 2: kk1, m0/m1 ----
    __builtin_amdgcn_s_barrier();
    bf0 = LD8(Bp + boff[0][1]); bf1 = LD8(Bp + boff[1][1]);
    bf2 = LD8(Bp + boff[2][1]); bf3 = LD8(Bp + boff[3][1]);
    a0 = LD8(Ap + aoff[0][1]);  a1 = LD8(Ap + aoff[1][1]);
    if (stg) {
      gload_lds16(Bb + (size_t)sb_row[0] * K + kt2 + sb_col[0], &Bs[st][0] + sb_dst[0]);
      gload_lds16(Bb + (size_t)sb_row[1] * K + kt2 + sb_col[1], &Bs[st][0] + sb_dst[1]);
    }
    __builtin_amdgcn_s_setprio(1);
    acc[0][0] = __builtin_amdgcn_mfma_f32_16x16x32_bf16(a0, bf0, acc[0][0], 0, 0, 0);
    acc[0][1] = __builtin_amdgcn_mfma_f32_16x16x32_bf16(a0, bf1, acc[0][1], 0, 0, 0);
    acc[0][2] = __builtin_amdgcn_mfma_f32_16x16x32_bf16(a0, bf2, acc[0][2], 0, 0, 0);
    acc[0][3] = __builtin_amdgcn_mfma_f32_16x16x32_bf16(a0, bf3, acc[0][3], 0, 0, 0);
    acc[1][0] = __builtin_amdgcn_mfma_f32_16x16x32_bf16(a1, bf0, acc[1][0], 0, 0, 0);
    acc[1][1] = __builtin_amdgcn_mfma_f32_16x16x32_bf16(a1, bf1, acc[1][1], 0, 0, 0);
    acc[1][2] = __builtin_amdgcn_mfma_f32_16x16x32_bf16(a1, bf2, acc[1][2], 0, 0, 0);
    acc[1][3] = __builtin_amdgcn_mfma_f32_16x16x32_bf16(a1, bf3, acc[1][3], 0, 0, 0);
    __builtin_amdgcn_s_setprio(0);

    // ---- phase 3: kk1, m2/m3 ----
    __builtin_amdgcn_s_barrier();
    a0 = LD8(Ap + aoff[2][1]);  a1 = LD8(Ap + aoff[3][1]);
    __builtin_amdgcn_s_setprio(1);
    acc[2][0] = __builtin_amdgcn_mfma_f32_16x16x32_bf16(a0, bf0, acc[2][0], 0, 0, 0);
    acc[2][1] = __builtin_amdgcn_mfma_f32_16x16x32_bf16(a0, bf1, acc[2][1], 0, 0, 0);
    acc[2][2] = __builtin_amdgcn_mfma_f32_16x16x32_bf16(a0, bf2, acc[2][2], 0, 0, 0);
    acc[2][3] = __builtin_amdgcn_mfma_f32_16x16x32_bf16(a0, bf3, acc[2][3], 0, 0, 0);
    acc[3][0] = __builtin_amdgcn_mfma_f32_16x16x32_bf16(a1, bf0, acc[3][0], 0, 0, 0);
    acc[3][1] = __builtin_amdgcn_mfma_f32_16x16x32_bf16(a1, bf1, acc[3][1], 0, 0, 0);
    acc[3][2] = __builtin_amdgcn_mfma_f32_16x16x32_bf16(a1, bf2, acc[3][2], 0, 0, 0);
    acc[3][3] = __builtin_amdgcn_mfma_f32_16x16x32_bf16(a1, bf3, acc[3][3], 0, 0, 0);
    __builtin_amdgcn_s_setprio(0);

    bu = (bu == 2) ? 0 : bu + 1;
    st = (st == 2) ? 0 : st + 1;
  }

#pragma unroll
  for (int m = 0; m < 4; m++) {
    int row0 = bm * 256 + wm * 64 + m * 16 + lg * 4;
#pragma unroll
    for (int n = 0; n < 4; n++) {
      int col = bn * 128 + wn * 64 + n * 16 + lr;
#pragma unroll
      for (int i = 0; i < 4; i++)
        C[(size_t)(row0 + i) * N + col] = (CT)acc[m][n][i];
    }
  }
}

// ---------------- RoPE + head-major reorder ----------------
__global__ __launch_bounds__(256) void k_rope(const bf16_t* __restrict__ qkv,
                                              const float* __restrict__ fcos,
                                              const float* __restrict__ fsin,
                                              bf16_t* __restrict__ dst,
                                              int nheads, int col_off, float mul) {
  int idx = blockIdx.x * 256 + threadIdx.x;   // B*S*nheads*64 threads
  int p = idx & 63;
  int h = (idx >> 6) % nheads;
  int bs = idx / (64 * nheads);
  int s = bs & (S_ - 1);
  int b = bs >> 11;                            // bs / S_
  const bf16_t* src = qkv + (size_t)bs * NQK_ + col_off + h * HD_ + 2 * p;
  bf16x2 ab = *(const bf16x2*)src;
  float a = (float)ab[0], bb = (float)ab[1];
  float c = fcos[s * 64 + p], sn = fsin[s * 64 + p];
  bf16x2 o = { (bf16_t)((a * c - bb * sn) * mul), (bf16_t)((a * sn + bb * c) * mul) };
  *(bf16x2*)(dst + ((((size_t)b * nheads + h) * S_ + s) * HD_) + 2 * p) = o;
}

// ---------------- V transpose: qkv v-cols -> vt[B][NKV][HD][S] ----------------
__global__ __launch_bounds__(256) void k_vtrans(const bf16_t* __restrict__ qkv,
                                                bf16_t* __restrict__ vtr) {
  __shared__ bf16_t tile[32][33];
  int s0 = blockIdx.x * 32, d0 = blockIdx.y * 32, z = blockIdx.z;  // z = b*NKV+kvh
  int b = z >> 3, kvh = z & 7;
  int tx = threadIdx.x, ty = threadIdx.y;
#pragma unroll
  for (int i = 0; i < 4; i++)
    tile[ty + 8*i][tx] =
        qkv[(size_t)(b * S_ + s0 + ty + 8*i) * NQK_ + (D_ + NKV_ * HD_) + kvh * HD_ + d0 + tx];
  __syncthreads();
#pragma unroll
  for (int i = 0; i < 4; i++)
    vtr[((size_t)z * HD_ + d0 + ty + 8*i) * S_ + s0 + tx] = tile[tx][ty + 8*i];
}

// ---------------- Flash attention (non-causal, GQA) ----------------
// grid (S/128, NH, B), 256 thr (4 waves). Wave w owns q rows [qb*128+w*32, +32)
// as two 16-row m-frags. K/V tiles (KVBLK=64) staged in LDS, double-buffered,
// XOR-swizzled (pre-swizzled global source, linear LDS dest per m173/rule21).
#define KVBLK 64
__global__ __launch_bounds__(256, 2) void k_flash(const bf16_t* __restrict__ qr,
                                                  const bf16_t* __restrict__ kr,
                                                  const bf16_t* __restrict__ vt,
                                                  bf16_t* __restrict__ ctx) {
  __shared__ __align__(16) bf16_t Ks[2][KVBLK * HD_];   // 2 x 16 KB [row s][col d]
  __shared__ __align__(16) bf16_t Vs[2][HD_ * KVBLK];   // 2 x 16 KB [row d][col s]
  __shared__ __align__(16) bf16_t plds[4][16][72];      // per-wave P scratch
  const int tid = threadIdx.x;
  const int l = tid & 63, w = tid >> 6;
  const int lr = l & 15, lg = l >> 4;
  const int qb = blockIdx.x, h = blockIdx.y, b = blockIdx.z;
  const int kvh = h >> 2;   // NREP=4

  const bf16_t* qbase = qr + (((size_t)b * NH_ + h) * S_ + qb * 128 + w * 32) * HD_;
  const bf16_t* kbase = kr + (((size_t)b * NKV_ + kvh) * S_) * HD_;
  const bf16_t* vbase = vt + (((size_t)b * NKV_ + kvh) * HD_) * S_;

  // Q fragments (pre-scaled by 1/sqrt(HD) in k_rope)
  bf16x8 qf[2][4];
#pragma unroll
  for (int m = 0; m < 2; m++)
#pragma unroll
    for (int kk = 0; kk < 4; kk++)
      qf[m][kk] = *(const bf16x8*)(qbase + (m * 16 + lr) * HD_ + kk * 32 + lg * 8);

  f32x4 o[2][8];
#pragma unroll
  for (int m = 0; m < 2; m++)
#pragma unroll
    for (int n = 0; n < 8; n++) o[m][n] = f32x4{0.f, 0.f, 0.f, 0.f};
  float mR[2][4], lR[2][4];
#pragma unroll
  for (int m = 0; m < 2; m++)
#pragma unroll
    for (int i = 0; i < 4; i++) { mR[m][i] = -1e30f; lR[m][i] = 0.f; }

  // stage tile t into buffer bu (K: 16KB, V: 16KB; 8 gload16/thread)
  auto stage = [&](int bu, int t) {
    const int kb = t * KVBLK;
#pragma unroll
    for (int j = 0; j < 4; j++) {
      int o_ = (tid + 256 * j) * 16;                 // byte offset in K tile
      int row = o_ >> 8, cb = o_ & 255;              // row stride 256B
      int scb = cb ^ ((row & 7) << 4);
      gload_lds16(kbase + (size_t)(kb + row) * HD_ + (scb >> 1),
                  &Ks[bu][0] + (o_ >> 1));
    }
#pragma unroll
    for (int j = 0; j < 4; j++) {
      int o_ = (tid + 256 * j) * 16;                 // byte offset in V tile
      int row = o_ >> 7, cb = o_ & 127;              // row stride 128B
      int scb = cb ^ ((row & 7) << 4);
      gload_lds16(vbase + (size_t)row * S_ + kb + (scb >> 1),
                  &Vs[bu][0] + (o_ >> 1));
    }
  };

  const int nt = S_ / KVBLK;
  stage(0, 0);
  __syncthreads();
  int buf = 0;

  for (int t = 0; t < nt; t++) {
    if (t + 1 < nt) stage(buf ^ 1, t + 1);
    const bf16_t* Kb = &Ks[buf][0];
    const bf16_t* Vb = &Vs[buf][0];

    // QK^T: sc[m][n], K frag shared across m
    f32x4 sc[2][4];
#pragma unroll
    for (int m = 0; m < 2; m++)
#pragma unroll
      for (int n = 0; n < 4; n++) sc[m][n] = f32x4{0.f, 0.f, 0.f, 0.f};
#pragma unroll
    for (int n = 0; n < 4; n++) {
#pragma unroll
      for (int kk = 0; kk < 4; kk++) {
        int r = n * 16 + lr;
        int cb = (kk * 64 + lg * 16) ^ ((r & 7) << 4);
        bf16x8 kf = *(const bf16x8*)(Kb + (((r << 8) + cb) >> 1));
        sc[0][n] = __builtin_amdgcn_mfma_f32_16x16x32_bf16(qf[0][kk], kf, sc[0][n], 0, 0, 0);
        sc[1][n] = __builtin_amdgcn_mfma_f32_16x16x32_bf16(qf[1][kk], kf, sc[1][n], 0, 0, 0);
      }
    }

    // online softmax per m-frag; P staged via per-wave LDS, read back to regs
    bf16x8 pf[2][2];
#pragma unroll
    for (int m = 0; m < 2; m++) {
      float alpha[4], psum[4];
#pragma unroll
      for (int i = 0; i < 4; i++) {
        float tmx = fmaxf(fmaxf(sc[m][0][i], sc[m][1][i]),
                          fmaxf(sc[m][2][i], sc[m][3][i]));
        tmx = fmaxf(tmx, __shfl_xor(tmx, 1));
        tmx = fmaxf(tmx, __shfl_xor(tmx, 2));
        tmx = fmaxf(tmx, __shfl_xor(tmx, 4));
        tmx = fmaxf(tmx, __shfl_xor(tmx, 8));
        float mnew = fmaxf(mR[m][i], tmx);
        alpha[i] = __expf(mR[m][i] - mnew);
        mR[m][i] = mnew;
        psum[i] = 0.f;
      }
#pragma unroll
      for (int n = 0; n < 4; n++)
#pragma unroll
        for (int i = 0; i < 4; i++) {
          float pv = __expf(sc[m][n][i] - mR[m][i]);
          psum[i] += pv;
          plds[w][lg * 4 + i][n * 16 + lr] = (bf16_t)pv;
        }
#pragma unroll
      for (int i = 0; i < 4; i++) {
        float t2 = psum[i];
        t2 += __shfl_xor(t2, 1);
        t2 += __shfl_xor(t2, 2);
        t2 += __shfl_xor(t2, 4);
        t2 += __shfl_xor(t2, 8);
        lR[m][i] = lR[m][i] * alpha[i] + t2;
      }
#pragma unroll
      for (int n = 0; n < 8; n++)
#pragma unroll
        for (int i = 0; i < 4; i++) o[m][n][i] *= alpha[i];
      pf[m][0] = *(const bf16x8*)(&plds[w][lr][lg * 8]);
      pf[m][1] = *(const bf16x8*)(&plds[w][lr][32 + lg * 8]);
    }

    // PV: V frag loaded once, shared across both m
#pragma unroll
    for (int n = 0; n < 8; n++) {
#pragma unroll
      for (int kk = 0; kk < 2; kk++) {
        int r = n * 16 + lr;
        int cb = (kk * 64 + lg * 16) ^ ((r & 7) << 4);
        bf16x8 vf = *(const bf16x8*)(Vb + (((r << 7) + cb) >> 1));
        o[0][n] = __builtin_amdgcn_mfma_f32_16x16x32_bf16(pf[0][kk], vf, o[0][n], 0, 0, 0);
        o[1][n] = __builtin_amdgcn_mfma_f32_16x16x32_bf16(pf[1][kk], vf, o[1][n], 0, 0, 0);
      }
    }
    __syncthreads();
    buf ^= 1;
  }

#pragma unroll
  for (int m = 0; m < 2; m++)
#pragma unroll
    for (int n = 0; n < 8; n++)
#pragma unroll
      for (int i = 0; i < 4; i++) {
        int srow = qb * 128 + w * 32 + m * 16 + lg * 4 + i;
        int d = n * 16 + lr;
        ctx[((size_t)(b * S_ + srow)) * D_ + h * HD_ + d] = (bf16_t)(o[m][n][i] / lR[m][i]);
      }
}

// ---------------- launch ----------------
extern "C" void kernel_launch(void* const* d_in, const int* in_sizes, int n_in,
                              void* d_out, int out_size, void* d_ws, size_t ws_size,
                              hipStream_t stream) {
  const float* x    = (const float*)d_in[0];
  const float* wq   = (const float*)d_in[1];
  const float* wk   = (const float*)d_in[2];
  const float* wv   = (const float*)d_in[3];
  const float* wo   = (const float*)d_in[4];
  const float* fcos = (const float*)d_in[5];
  const float* fsin = (const float*)d_in[6];
  float* out = (float*)d_out;

  // workspace layout (aliased; 160 MB total)
  const size_t SZ_XB    = (size_t)BS_ * D_ * 2;      // 32 MB  (xb, later qrope)
  const size_t SZ_WQKVT = (size_t)NQK_ * D_ * 2;     // 48 MB  (wqkvt, later krope+vtr)
  const size_t SZ_WOT   = (size_t)D_ * D_ * 2;       // 32 MB
  char* p = (char*)d_ws;
  bf16_t* xb    = (bf16_t*)p;                        // then qrope
  bf16_t* wqkvt = (bf16_t*)(p + SZ_XB);              // then krope, vtr
  bf16_t* wot   = (bf16_t*)(p + SZ_XB + SZ_WQKVT);
  bf16_t* qkv   = (bf16_t*)(p + SZ_XB + SZ_WQKVT + SZ_WOT);  // then ctx
  bf16_t* qrope = xb;
  bf16_t* krope = wqkvt;
  bf16_t* vtr   = wqkvt + (size_t)BS_ * NKV_ * HD_;
  bf16_t* ctx   = qkv;

  dim3 tb(32, 8);
  // 1. x -> bf16
  k_cvt<<<BS_ * D_ / 1024, 256, 0, stream>>>((const float4*)x, (bf16x4*)xb, BS_ * D_ / 4);
  // 2. transpose+convert weights (fused qkv weight, then wo)
  k_transpose_cvt<<<dim3(D_ / 32, D_ / 32), tb, 0, stream>>>(wq, wqkvt, D_, D_);
  k_transpose_cvt<<<dim3(32, D_ / 32), tb, 0, stream>>>(wk, wqkvt + (size_t)D_ * D_, D_, NKV_ * HD_);
  k_transpose_cvt<<<dim3(32, D_ / 32), tb, 0, stream>>>(wv, wqkvt + (size_t)(D_ + NKV_ * HD_) * D_, D_, NKV_ * HD_);
  k_transpose_cvt<<<dim3(D_ / 32, D_ / 32), tb, 0, stream>>>(wo, wot, D_, D_);
  // 3. fused QKV projection (grid 48x16 = 768 blocks = 3 full rounds)
  k_gemm256<bf16_t><<<dim3(NQK_ / 128, BS_ / 256), 512, 0, stream>>>(xb, wqkvt, qkv, BS_, NQK_, D_);
  // 4. RoPE + reorder (Q pre-scaled by 1/sqrt(HD)), V transpose
  k_rope<<<BS_ * NH_ * 64 / 256, 256, 0, stream>>>(qkv, fcos, fsin, qrope, NH_, 0, 0.08838834764831845f);
  k_rope<<<BS_ * NKV_ * 64 / 256, 256, 0, stream>>>(qkv, fcos, fsin, krope, NKV_, D_, 1.0f);
  k_vtrans<<<dim3(S_ / 32, HD_ / 32, B_ * NKV_), tb, 0, stream>>>(qkv, vtr);
  // 5. flash attention
  k_flash<<<dim3(S_ / 128, NH_, B_), 256, 0, stream>>>(qrope, krope, vtr, ctx);
  // 6. output projection -> f32 out (grid 32x16 = 512 blocks = 2 full rounds)
  k_gemm256<float><<<dim3(D_ / 128, BS_ / 256), 512, 0, stream>>>(ctx, wot, out, BS_, D_, D_);
}

// Round 5
// 775.369 us; speedup vs baseline: 1.0679x; 1.0389x over previous
//
#include <hip/hip_runtime.h>
#include <hip/hip_bf16.h>
#include <cstdint>

#define B_   2
#define S_   2048
#define D_   4096
#define NH_  32
#define NKV_ 8
#define HD_  128
#define BS_  (B_*S_)      // 4096 rows
#define NQK_ 6144         // NH*HD + 2*NKV*HD

typedef __bf16 bf16_t;
typedef __bf16 bf16x8 __attribute__((ext_vector_type(8)));
typedef __bf16 bf16x4 __attribute__((ext_vector_type(4)));
typedef __bf16 bf16x2 __attribute__((ext_vector_type(2)));
typedef float  f32x4  __attribute__((ext_vector_type(4)));

typedef const __attribute__((address_space(1))) void* gas_ptr;
typedef __attribute__((address_space(3))) void* las_ptr;

__device__ __forceinline__ void gload_lds16(const void* g, void* l) {
  __builtin_amdgcn_global_load_lds((gas_ptr)g, (las_ptr)l, 16, 0, 0);
}

#define LD8(p) (*(const bf16x8*)(p))
#define MFMA(a, b, c) __builtin_amdgcn_mfma_f32_16x16x32_bf16(a, b, c, 0, 0, 0)

// ---------------- f32 -> bf16 convert (vectorized) ----------------
__global__ __launch_bounds__(256) void k_cvt(const float4* __restrict__ in,
                                             bf16x4* __restrict__ out, int n4) {
  int i = blockIdx.x * 256 + threadIdx.x;
  if (i >= n4) return;
  float4 v = in[i];
  bf16x4 o = { (bf16_t)v.x, (bf16_t)v.y, (bf16_t)v.z, (bf16_t)v.w };
  out[i] = o;
}

// ---------------- w[K][N] f32 -> wt[N][K] bf16 (tiled transpose) ----------------
__global__ __launch_bounds__(256) void k_transpose_cvt(const float* __restrict__ w,
                                                       bf16_t* __restrict__ wt,
                                                       int K, int N) {
  __shared__ float tile[32][33];
  int n0 = blockIdx.x * 32, k0 = blockIdx.y * 32;
  int tx = threadIdx.x, ty = threadIdx.y;   // 32x8
#pragma unroll
  for (int i = 0; i < 4; i++)
    tile[ty + 8*i][tx] = w[(size_t)(k0 + ty + 8*i) * N + n0 + tx];
  __syncthreads();
#pragma unroll
  for (int i = 0; i < 4; i++)
    wt[(size_t)(n0 + ty + 8*i) * K + k0 + tx] = (bf16_t)tile[tx][ty + 8*i];
}

// ---------------- 256x128 NT GEMM, 1-barrier/K-tile pipeline, triple buffer ----
// C[M][N] = A[M][K] @ Bt[N][K]^T. BK=64, 8 waves (4m x 2n), per-wave 64x64.
// LDS: 3 bufs x (A 32KB + B 16KB) = 144 KB. Tile t read from buf t%3; during
// tile t we stage tile t+2 into (t+2)%3 (its readers, tile t-1, finished before
// the (t-1 -> t) barrier; a wave ahead in t+1 stages t%3 only after the t-end
// barrier which all tile-t readers reached -> race-free with ONE barrier/tile).
// Body: [LD8 kk0 x8][stage 6 gloads][LD8 kk1 x8][16 MFMA kk0 (kk1 loads in
// flight under them)][16 MFMA kk1][vmcnt(6) certifies buf t+1][barrier].
// Swizzle: byte ^= (row&7)<<4 within 128B rows, both-sides (pre-swizzled global
// source + swizzled ds_read) -> conflict-free b128 (round-4: conflicts == 0).
template <typename CT>
__global__ __launch_bounds__(512, 2) void k_gemmP(const bf16_t* __restrict__ A,
                                                  const bf16_t* __restrict__ Bt,
                                                  CT* __restrict__ C,
                                                  int M, int N, int K) {
  __shared__ __align__(16) bf16_t As[3][256 * 64];   // 3 x 32 KB
  __shared__ __align__(16) bf16_t Bs[3][128 * 64];   // 3 x 16 KB
  const int tid = threadIdx.x;
  const int l = tid & 63, w = tid >> 6;
  const int lr = l & 15, lg = l >> 4;
  const int wm = w >> 1, wn = w & 1;       // 4 x 2 wave grid

  // bn-major dispatch: consecutive blocks share the B-panel (bm = blockIdx.x)
  const int bm = blockIdx.x, bn = blockIdx.y;

  const bf16_t* Ab = A  + (size_t)bm * 256 * K;
  const bf16_t* Bb = Bt + (size_t)bn * 128 * K;

  // staging maps: linear LDS dest byte o; global source col pre-swizzled
  int sa_row[4], sa_col[4], sa_dst[4];
#pragma unroll
  for (int j = 0; j < 4; j++) {
    int o = (j * 512 + tid) * 16;
    int row = o >> 7, cb = o & 127;
    sa_row[j] = row;
    sa_col[j] = (cb ^ ((row & 7) << 4)) >> 1;
    sa_dst[j] = o >> 1;
  }
  int sb_row[2], sb_col[2], sb_dst[2];
#pragma unroll
  for (int j = 0; j < 2; j++) {
    int o = (j * 512 + tid) * 16;
    int row = o >> 7, cb = o & 127;
    sb_row[j] = row;
    sb_col[j] = (cb ^ ((row & 7) << 4)) >> 1;
    sb_dst[j] = o >> 1;
  }

  // fragment read offsets (elements, within one buffer; row = 64 elems = 128B)
  int aoff[4][2], boff[4][2];
#pragma unroll
  for (int m = 0; m < 4; m++)
#pragma unroll
    for (int kk = 0; kk < 2; kk++) {
      int r = wm * 64 + m * 16 + lr;
      aoff[m][kk] = r * 64 + (((kk * 64 + lg * 16) ^ ((r & 7) << 4)) >> 1);
    }
#pragma unroll
  for (int n = 0; n < 4; n++)
#pragma unroll
    for (int kk = 0; kk < 2; kk++) {
      int r = wn * 64 + n * 16 + lr;
      boff[n][kk] = r * 64 + (((kk * 64 + lg * 16) ^ ((r & 7) << 4)) >> 1);
    }

  f32x4 acc[4][4];
#pragma unroll
  for (int m = 0; m < 4; m++)
#pragma unroll
    for (int n = 0; n < 4; n++) acc[m][n] = f32x4{0.f, 0.f, 0.f, 0.f};

  auto stage = [&](int t) {
    const int bu = t % 3;
    const int kt = t << 6;
#pragma unroll
    for (int j = 0; j < 4; j++)
      gload_lds16(Ab + (size_t)sa_row[j] * K + kt + sa_col[j], &As[bu][0] + sa_dst[j]);
#pragma unroll
    for (int j = 0; j < 2; j++)
      gload_lds16(Bb + (size_t)sb_row[j] * K + kt + sb_col[j], &Bs[bu][0] + sb_dst[j]);
  };

  const int NT = K >> 6;
  stage(0);
  stage(1);
  asm volatile("s_waitcnt vmcnt(6)" ::: "memory");  // buf0 (own slice) landed
  __builtin_amdgcn_s_barrier();                      // -> buf0 globally complete

  int bu = 0;
  for (int t = 0; t < NT; ++t) {
    const bf16_t* Ap = &As[bu][0];
    const bf16_t* Bp = &Bs[bu][0];
    bf16x8 a0_[4], b0_[4], a1_[4], b1_[4];
    // kk0 reads first (their latency is the exposed one)
#pragma unroll
    for (int m = 0; m < 4; m++) a0_[m] = LD8(Ap + aoff[m][0]);
#pragma unroll
    for (int n = 0; n < 4; n++) b0_[n] = LD8(Bp + boff[n][0]);
    // stage tile t+2 (buf (t+2)%3): readers (tile t-1) done before last barrier
    if (t + 2 < NT) stage(t + 2);
    // kk1 reads: in flight under kk0's MFMAs (compiler waits kk0 regs only)
#pragma unroll
    for (int m = 0; m < 4; m++) a1_[m] = LD8(Ap + aoff[m][1]);
#pragma unroll
    for (int n = 0; n < 4; n++) b1_[n] = LD8(Bp + boff[n][1]);

    __builtin_amdgcn_s_setprio(1);
#pragma unroll
    for (int m = 0; m < 4; m++)
#pragma unroll
      for (int n = 0; n < 4; n++)
        acc[m][n] = MFMA(a0_[m], b0_[n], acc[m][n]);
    __builtin_amdgcn_s_setprio(0);
    __builtin_amdgcn_s_setprio(1);
#pragma unroll
    for (int m = 0; m < 4; m++)
#pragma unroll
      for (int n = 0; n < 4; n++)
        acc[m][n] = MFMA(a1_[m], b1_[n], acc[m][n]);
    __builtin_amdgcn_s_setprio(0);

    if (t + 1 < NT) {
      if (t + 2 < NT) asm volatile("s_waitcnt vmcnt(6)" ::: "memory");
      else            asm volatile("s_waitcnt vmcnt(0)" ::: "memory");
    }
    __builtin_amdgcn_s_barrier();
    bu = (bu == 2) ? 0 : bu + 1;
  }

#pragma unroll
  for (int m = 0; m < 4; m++) {
    int row0 = bm * 256 + wm * 64 + m * 16 + lg * 4;
#pragma unroll
    for (int n = 0; n < 4; n++) {
      int col = bn * 128 + wn * 64 + n * 16 + lr;
#pragma unroll
      for (int i = 0; i < 4; i++)
        C[(size_t)(row0 + i) * N + col] = (CT)acc[m][n][i];
    }
  }
}

// ---------------- RoPE + head-major reorder ----------------
__global__ __launch_bounds__(256) void k_rope(const bf16_t* __restrict__ qkv,
                                              const float* __restrict__ fcos,
                                              const float* __restrict__ fsin,
                                              bf16_t* __restrict__ dst,
                                              int nheads, int col_off, float mul) {
  int idx = blockIdx.x * 256 + threadIdx.x;   // B*S*nheads*64 threads
  int p = idx & 63;
  int h = (idx >> 6) % nheads;
  int bs = idx / (64 * nheads);
  int s = bs & (S_ - 1);
  int b = bs >> 11;                            // bs / S_
  const bf16_t* src = qkv + (size_t)bs * NQK_ + col_off + h * HD_ + 2 * p;
  bf16x2 ab = *(const bf16x2*)src;
  float a = (float)ab[0], bb = (float)ab[1];
  float c = fcos[s * 64 + p], sn = fsin[s * 64 + p];
  bf16x2 o = { (bf16_t)((a * c - bb * sn) * mul), (bf16_t)((a * sn + bb * c) * mul) };
  *(bf16x2*)(dst + ((((size_t)b * nheads + h) * S_ + s) * HD_) + 2 * p) = o;
}

// ---------------- V transpose: qkv v-cols -> vt[B][NKV][HD][S] ----------------
__global__ __launch_bounds__(256) void k_vtrans(const bf16_t* __restrict__ qkv,
                                                bf16_t* __restrict__ vtr) {
  __shared__ bf16_t tile[32][33];
  int s0 = blockIdx.x * 32, d0 = blockIdx.y * 32, z = blockIdx.z;  // z = b*NKV+kvh
  int b = z >> 3, kvh = z & 7;
  int tx = threadIdx.x, ty = threadIdx.y;
#pragma unroll
  for (int i = 0; i < 4; i++)
    tile[ty + 8*i][tx] =
        qkv[(size_t)(b * S_ + s0 + ty + 8*i) * NQK_ + (D_ + NKV_ * HD_) + kvh * HD_ + d0 + tx];
  __syncthreads();
#pragma unroll
  for (int i = 0; i < 4; i++)
    vtr[((size_t)z * HD_ + d0 + ty + 8*i) * S_ + s0 + tx] = tile[tx][ty + 8*i];
}

// ---------------- Flash attention (non-causal, GQA) ----------------
// grid (S/128, NH, B), 256 thr (4 waves). Wave w owns q rows [qb*128+w*32, +32)
// as two 16-row m-frags. K/V tiles (KVBLK=64) staged in LDS, double-buffered,
// XOR-swizzled (pre-swizzled global source, linear LDS dest per m173/rule21).
#define KVBLK 64
__global__ __launch_bounds__(256, 2) void k_flash(const bf16_t* __restrict__ qr,
                                                  const bf16_t* __restrict__ kr,
                                                  const bf16_t* __restrict__ vt,
                                                  bf16_t* __restrict__ ctx) {
  __shared__ __align__(16) bf16_t Ks[2][KVBLK * HD_];   // 2 x 16 KB [row s][col d]
  __shared__ __align__(16) bf16_t Vs[2][HD_ * KVBLK];   // 2 x 16 KB [row d][col s]
  __shared__ __align__(16) bf16_t plds[4][16][72];      // per-wave P scratch
  const int tid = threadIdx.x;
  const int l = tid & 63, w = tid >> 6;
  const int lr = l & 15, lg = l >> 4;
  const int qb = blockIdx.x, h = blockIdx.y, b = blockIdx.z;
  const int kvh = h >> 2;   // NREP=4

  const bf16_t* qbase = qr + (((size_t)b * NH_ + h) * S_ + qb * 128 + w * 32) * HD_;
  const bf16_t* kbase = kr + (((size_t)b * NKV_ + kvh) * S_) * HD_;
  const bf16_t* vbase = vt + (((size_t)b * NKV_ + kvh) * HD_) * S_;

  // Q fragments (pre-scaled by 1/sqrt(HD) in k_rope)
  bf16x8 qf[2][4];
#pragma unroll
  for (int m = 0; m < 2; m++)
#pragma unroll
    for (int kk = 0; kk < 4; kk++)
      qf[m][kk] = *(const bf16x8*)(qbase + (m * 16 + lr) * HD_ + kk * 32 + lg * 8);

  f32x4 o[2][8];
#pragma unroll
  for (int m = 0; m < 2; m++)
#pragma unroll
    for (int n = 0; n < 8; n++) o[m][n] = f32x4{0.f, 0.f, 0.f, 0.f};
  float mR[2][4], lR[2][4];
#pragma unroll
  for (int m = 0; m < 2; m++)
#pragma unroll
    for (int i = 0; i < 4; i++) { mR[m][i] = -1e30f; lR[m][i] = 0.f; }

  // stage tile t into buffer bu (K: 16KB, V: 16KB; 8 gload16/thread)
  auto stage = [&](int bu, int t) {
    const int kb = t * KVBLK;
#pragma unroll
    for (int j = 0; j < 4; j++) {
      int o_ = (tid + 256 * j) * 16;                 // byte offset in K tile
      int row = o_ >> 8, cb = o_ & 255;              // row stride 256B
      int scb = cb ^ ((row & 7) << 4);
      gload_lds16(kbase + (size_t)(kb + row) * HD_ + (scb >> 1),
                  &Ks[bu][0] + (o_ >> 1));
    }
#pragma unroll
    for (int j = 0; j < 4; j++) {
      int o_ = (tid + 256 * j) * 16;                 // byte offset in V tile
      int row = o_ >> 7, cb = o_ & 127;              // row stride 128B
      int scb = cb ^ ((row & 7) << 4);
      gload_lds16(vbase + (size_t)row * S_ + kb + (scb >> 1),
                  &Vs[bu][0] + (o_ >> 1));
    }
  };

  const int nt = S_ / KVBLK;
  stage(0, 0);
  __syncthreads();
  int buf = 0;

  for (int t = 0; t < nt; t++) {
    if (t + 1 < nt) stage(buf ^ 1, t + 1);
    const bf16_t* Kb = &Ks[buf][0];
    const bf16_t* Vb = &Vs[buf][0];

    // QK^T: sc[m][n], K frag shared across m
    f32x4 sc[2][4];
#pragma unroll
    for (int m = 0; m < 2; m++)
#pragma unroll
      for (int n = 0; n < 4; n++) sc[m][n] = f32x4{0.f, 0.f, 0.f, 0.f};
#pragma unroll
    for (int n = 0; n < 4; n++) {
#pragma unroll
      for (int kk = 0; kk < 4; kk++) {
        int r = n * 16 + lr;
        int cb = (kk * 64 + lg * 16) ^ ((r & 7) << 4);
        bf16x8 kf = *(const bf16x8*)(Kb + (((r << 8) + cb) >> 1));
        sc[0][n] = MFMA(qf[0][kk], kf, sc[0][n]);
        sc[1][n] = MFMA(qf[1][kk], kf, sc[1][n]);
      }
    }

    // online softmax per m-frag; P staged via per-wave LDS, read back to regs
    bf16x8 pf[2][2];
#pragma unroll
    for (int m = 0; m < 2; m++) {
      float alpha[4], psum[4];
#pragma unroll
      for (int i = 0; i < 4; i++) {
        float tmx = fmaxf(fmaxf(sc[m][0][i], sc[m][1][i]),
                          fmaxf(sc[m][2][i], sc[m][3][i]));
        tmx = fmaxf(tmx, __shfl_xor(tmx, 1));
        tmx = fmaxf(tmx, __shfl_xor(tmx, 2));
        tmx = fmaxf(tmx, __shfl_xor(tmx, 4));
        tmx = fmaxf(tmx, __shfl_xor(tmx, 8));
        float mnew = fmaxf(mR[m][i], tmx);
        alpha[i] = __expf(mR[m][i] - mnew);
        mR[m][i] = mnew;
        psum[i] = 0.f;
      }
#pragma unroll
      for (int n = 0; n < 4; n++)
#pragma unroll
        for (int i = 0; i < 4; i++) {
          float pv = __expf(sc[m][n][i] - mR[m][i]);
          psum[i] += pv;
          plds[w][lg * 4 + i][n * 16 + lr] = (bf16_t)pv;
        }
#pragma unroll
      for (int i = 0; i < 4; i++) {
        float t2 = psum[i];
        t2 += __shfl_xor(t2, 1);
        t2 += __shfl_xor(t2, 2);
        t2 += __shfl_xor(t2, 4);
        t2 += __shfl_xor(t2, 8);
        lR[m][i] = lR[m][i] * alpha[i] + t2;
      }
#pragma unroll
      for (int n = 0; n < 8; n++)
#pragma unroll
        for (int i = 0; i < 4; i++) o[m][n][i] *= alpha[i];
      pf[m][0] = *(const bf16x8*)(&plds[w][lr][lg * 8]);
      pf[m][1] = *(const bf16x8*)(&plds[w][lr][32 + lg * 8]);
    }

    // PV: V frag loaded once, shared across both m
#pragma unroll
    for (int n = 0; n < 8; n++) {
#pragma unroll
      for (int kk = 0; kk < 2; kk++) {
        int r = n * 16 + lr;
        int cb = (kk * 64 + lg * 16) ^ ((r & 7) << 4);
        bf16x8 vf = *(const bf16x8*)(Vb + (((r << 7) + cb) >> 1));
        o[0][n] = MFMA(pf[0][kk], vf, o[0][n]);
        o[1][n] = MFMA(pf[1][kk], vf, o[1][n]);
      }
    }
    __syncthreads();
    buf ^= 1;
  }

#pragma unroll
  for (int m = 0; m < 2; m++)
#pragma unroll
    for (int n = 0; n < 8; n++)
#pragma unroll
      for (int i = 0; i < 4; i++) {
        int srow = qb * 128 + w * 32 + m * 16 + lg * 4 + i;
        int d = n * 16 + lr;
        ctx[((size_t)(b * S_ + srow)) * D_ + h * HD_ + d] = (bf16_t)(o[m][n][i] / lR[m][i]);
      }
}

// ---------------- launch ----------------
extern "C" void kernel_launch(void* const* d_in, const int* in_sizes, int n_in,
                              void* d_out, int out_size, void* d_ws, size_t ws_size,
                              hipStream_t stream) {
  const float* x    = (const float*)d_in[0];
  const float* wq   = (const float*)d_in[1];
  const float* wk   = (const float*)d_in[2];
  const float* wv   = (const float*)d_in[3];
  const float* wo   = (const float*)d_in[4];
  const float* fcos = (const float*)d_in[5];
  const float* fsin = (const float*)d_in[6];
  float* out = (float*)d_out;

  // workspace layout (aliased; 160 MB total)
  const size_t SZ_XB    = (size_t)BS_ * D_ * 2;      // 32 MB  (xb, later qrope)
  const size_t SZ_WQKVT = (size_t)NQK_ * D_ * 2;     // 48 MB  (wqkvt, later krope+vtr)
  const size_t SZ_WOT   = (size_t)D_ * D_ * 2;       // 32 MB
  char* p = (char*)d_ws;
  bf16_t* xb    = (bf16_t*)p;                        // then qrope
  bf16_t* wqkvt = (bf16_t*)(p + SZ_XB);              // then krope, vtr
  bf16_t* wot   = (bf16_t*)(p + SZ_XB + SZ_WQKVT);
  bf16_t* qkv   = (bf16_t*)(p + SZ_XB + SZ_WQKVT + SZ_WOT);  // then ctx
  bf16_t* qrope = xb;
  bf16_t* krope = wqkvt;
  bf16_t* vtr   = wqkvt + (size_t)BS_ * NKV_ * HD_;
  bf16_t* ctx   = qkv;

  dim3 tb(32, 8);
  // 1. x -> bf16
  k_cvt<<<BS_ * D_ / 1024, 256, 0, stream>>>((const float4*)x, (bf16x4*)xb, BS_ * D_ / 4);
  // 2. transpose+convert weights (fused qkv weight, then wo)
  k_transpose_cvt<<<dim3(D_ / 32, D_ / 32), tb, 0, stream>>>(wq, wqkvt, D_, D_);
  k_transpose_cvt<<<dim3(32, D_ / 32), tb, 0, stream>>>(wk, wqkvt + (size_t)D_ * D_, D_, NKV_ * HD_);
  k_transpose_cvt<<<dim3(32, D_ / 32), tb, 0, stream>>>(wv, wqkvt + (size_t)(D_ + NKV_ * HD_) * D_, D_, NKV_ * HD_);
  k_transpose_cvt<<<dim3(D_ / 32, D_ / 32), tb, 0, stream>>>(wo, wot, D_, D_);
  // 3. fused QKV projection (grid bm-x, bn-y: consecutive blocks share B-panel)
  k_gemmP<bf16_t><<<dim3(BS_ / 256, NQK_ / 128), 512, 0, stream>>>(xb, wqkvt, qkv, BS_, NQK_, D_);
  // 4. RoPE + reorder (Q pre-scaled by 1/sqrt(HD)), V transpose
  k_rope<<<BS_ * NH_ * 64 / 256, 256, 0, stream>>>(qkv, fcos, fsin, qrope, NH_, 0, 0.08838834764831845f);
  k_rope<<<BS_ * NKV_ * 64 / 256, 256, 0, stream>>>(qkv, fcos, fsin, krope, NKV_, D_, 1.0f);
  k_vtrans<<<dim3(S_ / 32, HD_ / 32, B_ * NKV_), tb, 0, stream>>>(qkv, vtr);
  // 5. flash attention
  k_flash<<<dim3(S_ / 128, NH_, B_), 256, 0, stream>>>(qrope, krope, vtr, ctx);
  // 6. output projection -> f32 out
  k_gemmP<float><<<dim3(BS_ / 256, D_ / 128), 512, 0, stream>>>(ctx, wot, out, BS_, D_, D_);
}

// Round 6
// 724.067 us; speedup vs baseline: 1.1436x; 1.0709x over previous
//
#include <hip/hip_runtime.h>
#include <hip/hip_bf16.h>
#include <cstdint>

#define B_   2
#define S_   2048
#define D_   4096
#define NH_  32
#define NKV_ 8
#define HD_  128
#define BS_  (B_*S_)      // 4096 rows
#define NQK_ 6144         // NH*HD + 2*NKV*HD

typedef __bf16 bf16_t;
typedef __bf16 bf16x8 __attribute__((ext_vector_type(8)));
typedef __bf16 bf16x4 __attribute__((ext_vector_type(4)));
typedef __bf16 bf16x2 __attribute__((ext_vector_type(2)));
typedef float  f32x4  __attribute__((ext_vector_type(4)));

typedef const __attribute__((address_space(1))) void* gas_ptr;
typedef __attribute__((address_space(3))) void* las_ptr;

__device__ __forceinline__ void gload_lds16(const void* g, void* l) {
  __builtin_amdgcn_global_load_lds((gas_ptr)g, (las_ptr)l, 16, 0, 0);
}

#define LD8(p) (*(const bf16x8*)(p))
#define MFMA(a, b, c) __builtin_amdgcn_mfma_f32_16x16x32_bf16(a, b, c, 0, 0, 0)

// ---------------- f32 -> bf16 convert (vectorized) ----------------
__global__ __launch_bounds__(256) void k_cvt(const float4* __restrict__ in,
                                             bf16x4* __restrict__ out, int n4) {
  int i = blockIdx.x * 256 + threadIdx.x;
  if (i >= n4) return;
  float4 v = in[i];
  bf16x4 o = { (bf16_t)v.x, (bf16_t)v.y, (bf16_t)v.z, (bf16_t)v.w };
  out[i] = o;
}

// ---------------- w[K][N] f32 -> wt[N][K] bf16 (tiled transpose) ----------------
__global__ __launch_bounds__(256) void k_transpose_cvt(const float* __restrict__ w,
                                                       bf16_t* __restrict__ wt,
                                                       int K, int N) {
  __shared__ float tile[32][33];
  int n0 = blockIdx.x * 32, k0 = blockIdx.y * 32;
  int tx = threadIdx.x, ty = threadIdx.y;   // 32x8
#pragma unroll
  for (int i = 0; i < 4; i++)
    tile[ty + 8*i][tx] = w[(size_t)(k0 + ty + 8*i) * N + n0 + tx];
  __syncthreads();
#pragma unroll
  for (int i = 0; i < 4; i++)
    wt[(size_t)(n0 + ty + 8*i) * K + k0 + tx] = (bf16_t)tile[tx][ty + 8*i];
}

// ---------------- 256x256 NT GEMM — m201-style 4-phase/K-tile template ---------
// C[M][N] = A[M][K] @ Bt[N][K]^T. BK=64, 8 waves (2M x 4N), wave tile 128x64.
// LDS: 2 dbuf x (A[256][64] + B[256][64]) = 128 KB. K-tile k lives in dbuf[k&1].
// Phases per K-tile (each: reads+stage -> s_barrier -> lgkmcnt(0) -> 16 MFMA ->
// s_barrier):
//   P0: read b[4]·kk0 + a[0..3]·kk0 ; stage A-half0(k+1)
//   P1: read a[4..7]·kk0            ; stage A-half1(k+1)
//   P2: read b[4]·kk1 + a[0..3]·kk1 ; (no stage: B-slots of dbuf[k&1] busy)
//   P3: read a[4..7]·kk1            ; stage B-half0/1(k+2) ; vmcnt(4)
// Stream order: ..., B(k+1)@(k-1)P3, A(k+1)@kP0/P1, B(k+2)@kP3 -> vmcnt(4) at
// P3 certifies through A(k+1) leaving B(k+2) in flight (never drains, T4).
// WAR: A-slots dbuf[(k+1)&1] freed at (k-1)P3's trailing barrier; B-slots of
// dbuf[k&1] freed at kP2's trailing barrier -> all stage issues race-free.
// Swizzle: byte ^= (row&7)<<4 in 128B rows, both sides (src pre-swizzle +
// swizzled ds_read); kk1 offsets = kk0 ^ 32 elements (pure XOR).
template <typename CT>
__global__ __launch_bounds__(512, 2) void k_gemm8p(const bf16_t* __restrict__ A,
                                                   const bf16_t* __restrict__ Bt,
                                                   CT* __restrict__ C,
                                                   int M, int N, int K) {
  __shared__ __align__(16) bf16_t As[2][256 * 64];   // 2 x 32 KB
  __shared__ __align__(16) bf16_t Bs[2][256 * 64];   // 2 x 32 KB
  const int tid = threadIdx.x;
  const int l = tid & 63, w = tid >> 6;
  const int lr = l & 15, lg = l >> 4;
  const int wm = w >> 2, wn = w & 3;       // 2M x 4N wave grid

  // XCD-chunked bijective swizzle, bn-fast (A-panel reuse inside a chunk)
  const int gx = gridDim.x;                 // N/256
  const int nwg = gx * gridDim.y;
  int bid = blockIdx.y * gx + blockIdx.x;
  bid = (bid & 7) * (nwg >> 3) + (bid >> 3);
  const int bm = bid / gx, bn = bid % gx;

  const bf16_t* Ab = A  + (size_t)bm * 256 * K;
  const bf16_t* Bb = Bt + (size_t)bn * 256 * K;

  // staging map: thread's 2 x 16B slice of a 128-row half-tile (16 KB)
  int st_row[2], st_col[2], st_dst[2];
#pragma unroll
  for (int j = 0; j < 2; j++) {
    int o = (j * 512 + tid) * 16;          // byte offset in half-tile
    int row = o >> 7, cb = o & 127;        // 128B rows
    st_row[j] = row;
    st_col[j] = (cb ^ ((row & 7) << 4)) >> 1;   // pre-swizzled source col (elems)
    st_dst[j] = o >> 1;                         // linear LDS dest (elems)
  }

  // fragment read offsets (kk0; kk1 = ^32)
  int aoff[8], boff[4];
#pragma unroll
  for (int m = 0; m < 8; m++) {
    int r = wm * 128 + m * 16 + lr;
    aoff[m] = r * 64 + (((lg * 16) ^ ((r & 7) << 4)) >> 1);
  }
#pragma unroll
  for (int n = 0; n < 4; n++) {
    int r = wn * 64 + n * 16 + lr;
    boff[n] = r * 64 + (((lg * 16) ^ ((r & 7) << 4)) >> 1);
  }

  f32x4 acc[8][4];
#pragma unroll
  for (int m = 0; m < 8; m++)
#pragma unroll
    for (int n = 0; n < 4; n++) acc[m][n] = f32x4{0.f, 0.f, 0.f, 0.f};

  // stage half-tile h (0=A half0, 1=A half1, 2=B half0, 3=B half1) of K-tile k
  auto stageH = [&](int k, int h) {
    const int kt = k << 6;
    const bf16_t* gb = (h < 2) ? Ab : Bb;
    bf16_t* lb = (h < 2) ? &As[k & 1][0] : &Bs[k & 1][0];
    const int rof = (h & 1) << 7;          // 0 or 128 rows
#pragma unroll
    for (int j = 0; j < 2; j++)
      gload_lds16(gb + (size_t)(st_row[j] + rof) * K + kt + st_col[j],
                  lb + (rof << 6) + st_dst[j]);
  };

  const int NT = K >> 6;
  // prologue stream: A0(0) A1(0) B0(0) B1(0) B0(1) B1(1)
  stageH(0, 0); stageH(0, 1); stageH(0, 2); stageH(0, 3);
  stageH(1, 2); stageH(1, 3);
  asm volatile("s_waitcnt vmcnt(4)" ::: "memory");   // K-tile 0 landed; B(1) in flight
  __builtin_amdgcn_s_barrier();

  for (int k = 0; k < NT; ++k) {
    const bf16_t* Ap = &As[k & 1][0];
    const bf16_t* Bp = &Bs[k & 1][0];
    const bool s1 = (k + 1 < NT), s2 = (k + 2 < NT);
    bf16x8 bfr[4], a[4];

    // ---- P0: b kk0 + a[0..3] kk0 ; stage A-half0(k+1) ----
#pragma unroll
    for (int n = 0; n < 4; n++) bfr[n] = LD8(Bp + boff[n]);
#pragma unroll
    for (int m = 0; m < 4; m++) a[m] = LD8(Ap + aoff[m]);
    if (s1) stageH(k + 1, 0);
    __builtin_amdgcn_s_barrier();
    asm volatile("s_waitcnt lgkmcnt(0)" ::: "memory");
    __builtin_amdgcn_s_setprio(1);
#pragma unroll
    for (int m = 0; m < 4; m++)
#pragma unroll
      for (int n = 0; n < 4; n++)
        acc[m][n] = MFMA(a[m], bfr[n], acc[m][n]);
    __builtin_amdgcn_s_setprio(0);
    __builtin_amdgcn_s_barrier();

    // ---- P1: a[4..7] kk0 ; stage A-half1(k+1) ----
#pragma unroll
    for (int m = 0; m < 4; m++) a[m] = LD8(Ap + aoff[m + 4]);
    if (s1) stageH(k + 1, 1);
    __builtin_amdgcn_s_barrier();
    asm volatile("s_waitcnt lgkmcnt(0)" ::: "memory");
    __builtin_amdgcn_s_setprio(1);
#pragma unroll
    for (int m = 0; m < 4; m++)
#pragma unroll
      for (int n = 0; n < 4; n++)
        acc[m + 4][n] = MFMA(a[m], bfr[n], acc[m + 4][n]);
    __builtin_amdgcn_s_setprio(0);
    __builtin_amdgcn_s_barrier();

    // ---- P2: b kk1 + a[0..3] kk1 ----
#pragma unroll
    for (int n = 0; n < 4; n++) bfr[n] = LD8(Bp + (boff[n] ^ 32));
#pragma unroll
    for (int m = 0; m < 4; m++) a[m] = LD8(Ap + (aoff[m] ^ 32));
    __builtin_amdgcn_s_barrier();
    asm volatile("s_waitcnt lgkmcnt(0)" ::: "memory");
    __builtin_amdgcn_s_setprio(1);
#pragma unroll
    for (int m = 0; m < 4; m++)
#pragma unroll
      for (int n = 0; n < 4; n++)
        acc[m][n] = MFMA(a[m], bfr[n], acc[m][n]);
    __builtin_amdgcn_s_setprio(0);
    __builtin_amdgcn_s_barrier();

    // ---- P3: a[4..7] kk1 ; stage B(k+2) ; boundary vmcnt ----
#pragma unroll
    for (int m = 0; m < 4; m++) a[m] = LD8(Ap + (aoff[m + 4] ^ 32));
    if (s2) { stageH(k + 2, 2); stageH(k + 2, 3); }
    if (s2)      asm volatile("s_waitcnt vmcnt(4)" ::: "memory");
    else if (s1) asm volatile("s_waitcnt vmcnt(0)" ::: "memory");
    __builtin_amdgcn_s_barrier();
    asm volatile("s_waitcnt lgkmcnt(0)" ::: "memory");
    __builtin_amdgcn_s_setprio(1);
#pragma unroll
    for (int m = 0; m < 4; m++)
#pragma unroll
      for (int n = 0; n < 4; n++)
        acc[m + 4][n] = MFMA(a[m], bfr[n], acc[m + 4][n]);
    __builtin_amdgcn_s_setprio(0);
    __builtin_amdgcn_s_barrier();
  }

#pragma unroll
  for (int m = 0; m < 8; m++) {
    int row0 = bm * 256 + wm * 128 + m * 16 + lg * 4;
#pragma unroll
    for (int n = 0; n < 4; n++) {
      int col = bn * 256 + wn * 64 + n * 16 + lr;
#pragma unroll
      for (int i = 0; i < 4; i++)
        C[(size_t)(row0 + i) * N + col] = (CT)acc[m][n][i];
    }
  }
}

// ---------------- RoPE + head-major reorder ----------------
__global__ __launch_bounds__(256) void k_rope(const bf16_t* __restrict__ qkv,
                                              const float* __restrict__ fcos,
                                              const float* __restrict__ fsin,
                                              bf16_t* __restrict__ dst,
                                              int nheads, int col_off, float mul) {
  int idx = blockIdx.x * 256 + threadIdx.x;   // B*S*nheads*64 threads
  int p = idx & 63;
  int h = (idx >> 6) % nheads;
  int bs = idx / (64 * nheads);
  int s = bs & (S_ - 1);
  int b = bs >> 11;                            // bs / S_
  const bf16_t* src = qkv + (size_t)bs * NQK_ + col_off + h * HD_ + 2 * p;
  bf16x2 ab = *(const bf16x2*)src;
  float a = (float)ab[0], bb = (float)ab[1];
  float c = fcos[s * 64 + p], sn = fsin[s * 64 + p];
  bf16x2 o = { (bf16_t)((a * c - bb * sn) * mul), (bf16_t)((a * sn + bb * c) * mul) };
  *(bf16x2*)(dst + ((((size_t)b * nheads + h) * S_ + s) * HD_) + 2 * p) = o;
}

// ---------------- V transpose: qkv v-cols -> vt[B][NKV][HD][S] ----------------
__global__ __launch_bounds__(256) void k_vtrans(const bf16_t* __restrict__ qkv,
                                                bf16_t* __restrict__ vtr) {
  __shared__ bf16_t tile[32][33];
  int s0 = blockIdx.x * 32, d0 = blockIdx.y * 32, z = blockIdx.z;  // z = b*NKV+kvh
  int b = z >> 3, kvh = z & 7;
  int tx = threadIdx.x, ty = threadIdx.y;
#pragma unroll
  for (int i = 0; i < 4; i++)
    tile[ty + 8*i][tx] =
        qkv[(size_t)(b * S_ + s0 + ty + 8*i) * NQK_ + (D_ + NKV_ * HD_) + kvh * HD_ + d0 + tx];
  __syncthreads();
#pragma unroll
  for (int i = 0; i < 4; i++)
    vtr[((size_t)z * HD_ + d0 + ty + 8*i) * S_ + s0 + tx] = tile[tx][ty + 8*i];
}

// ---------------- Flash attention (non-causal, GQA) ----------------
// grid (S/128, NH, B), 256 thr (4 waves). Wave w owns q rows [qb*128+w*32, +32)
// as two 16-row m-frags. K/V tiles (KVBLK=64) staged in LDS, double-buffered,
// XOR-swizzled (pre-swizzled global source, linear LDS dest per m173/rule21).
#define KVBLK 64
__global__ __launch_bounds__(256, 2) void k_flash(const bf16_t* __restrict__ qr,
                                                  const bf16_t* __restrict__ kr,
                                                  const bf16_t* __restrict__ vt,
                                                  bf16_t* __restrict__ ctx) {
  __shared__ __align__(16) bf16_t Ks[2][KVBLK * HD_];   // 2 x 16 KB [row s][col d]
  __shared__ __align__(16) bf16_t Vs[2][HD_ * KVBLK];   // 2 x 16 KB [row d][col s]
  __shared__ __align__(16) bf16_t plds[4][16][72];      // per-wave P scratch
  const int tid = threadIdx.x;
  const int l = tid & 63, w = tid >> 6;
  const int lr = l & 15, lg = l >> 4;
  const int qb = blockIdx.x, h = blockIdx.y, b = blockIdx.z;
  const int kvh = h >> 2;   // NREP=4

  const bf16_t* qbase = qr + (((size_t)b * NH_ + h) * S_ + qb * 128 + w * 32) * HD_;
  const bf16_t* kbase = kr + (((size_t)b * NKV_ + kvh) * S_) * HD_;
  const bf16_t* vbase = vt + (((size_t)b * NKV_ + kvh) * HD_) * S_;

  // Q fragments (pre-scaled by 1/sqrt(HD) in k_rope)
  bf16x8 qf[2][4];
#pragma unroll
  for (int m = 0; m < 2; m++)
#pragma unroll
    for (int kk = 0; kk < 4; kk++)
      qf[m][kk] = *(const bf16x8*)(qbase + (m * 16 + lr) * HD_ + kk * 32 + lg * 8);

  f32x4 o[2][8];
#pragma unroll
  for (int m = 0; m < 2; m++)
#pragma unroll
    for (int n = 0; n < 8; n++) o[m][n] = f32x4{0.f, 0.f, 0.f, 0.f};
  float mR[2][4], lR[2][4];
#pragma unroll
  for (int m = 0; m < 2; m++)
#pragma unroll
    for (int i = 0; i < 4; i++) { mR[m][i] = -1e30f; lR[m][i] = 0.f; }

  // stage tile t into buffer bu (K: 16KB, V: 16KB; 8 gload16/thread)
  auto stage = [&](int bu, int t) {
    const int kb = t * KVBLK;
#pragma unroll
    for (int j = 0; j < 4; j++) {
      int o_ = (tid + 256 * j) * 16;                 // byte offset in K tile
      int row = o_ >> 8, cb = o_ & 255;              // row stride 256B
      int scb = cb ^ ((row & 7) << 4);
      gload_lds16(kbase + (size_t)(kb + row) * HD_ + (scb >> 1),
                  &Ks[bu][0] + (o_ >> 1));
    }
#pragma unroll
    for (int j = 0; j < 4; j++) {
      int o_ = (tid + 256 * j) * 16;                 // byte offset in V tile
      int row = o_ >> 7, cb = o_ & 127;              // row stride 128B
      int scb = cb ^ ((row & 7) << 4);
      gload_lds16(vbase + (size_t)row * S_ + kb + (scb >> 1),
                  &Vs[bu][0] + (o_ >> 1));
    }
  };

  const int nt = S_ / KVBLK;
  stage(0, 0);
  __syncthreads();
  int buf = 0;

  for (int t = 0; t < nt; t++) {
    if (t + 1 < nt) stage(buf ^ 1, t + 1);
    const bf16_t* Kb = &Ks[buf][0];
    const bf16_t* Vb = &Vs[buf][0];

    // QK^T: sc[m][n], K frag shared across m
    f32x4 sc[2][4];
#pragma unroll
    for (int m = 0; m < 2; m++)
#pragma unroll
      for (int n = 0; n < 4; n++) sc[m][n] = f32x4{0.f, 0.f, 0.f, 0.f};
#pragma unroll
    for (int n = 0; n < 4; n++) {
#pragma unroll
      for (int kk = 0; kk < 4; kk++) {
        int r = n * 16 + lr;
        int cb = (kk * 64 + lg * 16) ^ ((r & 7) << 4);
        bf16x8 kf = *(const bf16x8*)(Kb + (((r << 8) + cb) >> 1));
        sc[0][n] = MFMA(qf[0][kk], kf, sc[0][n]);
        sc[1][n] = MFMA(qf[1][kk], kf, sc[1][n]);
      }
    }

    // online softmax per m-frag; P staged via per-wave LDS, read back to regs
    bf16x8 pf[2][2];
#pragma unroll
    for (int m = 0; m < 2; m++) {
      float alpha[4], psum[4];
#pragma unroll
      for (int i = 0; i < 4; i++) {
        float tmx = fmaxf(fmaxf(sc[m][0][i], sc[m][1][i]),
                          fmaxf(sc[m][2][i], sc[m][3][i]));
        tmx = fmaxf(tmx, __shfl_xor(tmx, 1));
        tmx = fmaxf(tmx, __shfl_xor(tmx, 2));
        tmx = fmaxf(tmx, __shfl_xor(tmx, 4));
        tmx = fmaxf(tmx, __shfl_xor(tmx, 8));
        float mnew = fmaxf(mR[m][i], tmx);
        alpha[i] = __expf(mR[m][i] - mnew);
        mR[m][i] = mnew;
        psum[i] = 0.f;
      }
#pragma unroll
      for (int n = 0; n < 4; n++)
#pragma unroll
        for (int i = 0; i < 4; i++) {
          float pv = __expf(sc[m][n][i] - mR[m][i]);
          psum[i] += pv;
          plds[w][lg * 4 + i][n * 16 + lr] = (bf16_t)pv;
        }
#pragma unroll
      for (int i = 0; i < 4; i++) {
        float t2 = psum[i];
        t2 += __shfl_xor(t2, 1);
        t2 += __shfl_xor(t2, 2);
        t2 += __shfl_xor(t2, 4);
        t2 += __shfl_xor(t2, 8);
        lR[m][i] = lR[m][i] * alpha[i] + t2;
      }
#pragma unroll
      for (int n = 0; n < 8; n++)
#pragma unroll
        for (int i = 0; i < 4; i++) o[m][n][i] *= alpha[i];
      pf[m][0] = *(const bf16x8*)(&plds[w][lr][lg * 8]);
      pf[m][1] = *(const bf16x8*)(&plds[w][lr][32 + lg * 8]);
    }

    // PV: V frag loaded once, shared across both m
#pragma unroll
    for (int n = 0; n < 8; n++) {
#pragma unroll
      for (int kk = 0; kk < 2; kk++) {
        int r = n * 16 + lr;
        int cb = (kk * 64 + lg * 16) ^ ((r & 7) << 4);
        bf16x8 vf = *(const bf16x8*)(Vb + (((r << 7) + cb) >> 1));
        o[0][n] = MFMA(pf[0][kk], vf, o[0][n]);
        o[1][n] = MFMA(pf[1][kk], vf, o[1][n]);
      }
    }
    __syncthreads();
    buf ^= 1;
  }

#pragma unroll
  for (int m = 0; m < 2; m++)
#pragma unroll
    for (int n = 0; n < 8; n++)
#pragma unroll
      for (int i = 0; i < 4; i++) {
        int srow = qb * 128 + w * 32 + m * 16 + lg * 4 + i;
        int d = n * 16 + lr;
        ctx[((size_t)(b * S_ + srow)) * D_ + h * HD_ + d] = (bf16_t)(o[m][n][i] / lR[m][i]);
      }
}

// ---------------- launch ----------------
extern "C" void kernel_launch(void* const* d_in, const int* in_sizes, int n_in,
                              void* d_out, int out_size, void* d_ws, size_t ws_size,
                              hipStream_t stream) {
  const float* x    = (const float*)d_in[0];
  const float* wq   = (const float*)d_in[1];
  const float* wk   = (const float*)d_in[2];
  const float* wv   = (const float*)d_in[3];
  const float* wo   = (const float*)d_in[4];
  const float* fcos = (const float*)d_in[5];
  const float* fsin = (const float*)d_in[6];
  float* out = (float*)d_out;

  // workspace layout (aliased; 160 MB total)
  const size_t SZ_XB    = (size_t)BS_ * D_ * 2;      // 32 MB  (xb, later qrope)
  const size_t SZ_WQKVT = (size_t)NQK_ * D_ * 2;     // 48 MB  (wqkvt, later krope+vtr)
  const size_t SZ_WOT   = (size_t)D_ * D_ * 2;       // 32 MB
  char* p = (char*)d_ws;
  bf16_t* xb    = (bf16_t*)p;                        // then qrope
  bf16_t* wqkvt = (bf16_t*)(p + SZ_XB);              // then krope, vtr
  bf16_t* wot   = (bf16_t*)(p + SZ_XB + SZ_WQKVT);
  bf16_t* qkv   = (bf16_t*)(p + SZ_XB + SZ_WQKVT + SZ_WOT);  // then ctx
  bf16_t* qrope = xb;
  bf16_t* krope = wqkvt;
  bf16_t* vtr   = wqkvt + (size_t)BS_ * NKV_ * HD_;
  bf16_t* ctx   = qkv;

  dim3 tb(32, 8);
  // 1. x -> bf16
  k_cvt<<<BS_ * D_ / 1024, 256, 0, stream>>>((const float4*)x, (bf16x4*)xb, BS_ * D_ / 4);
  // 2. transpose+convert weights (fused qkv weight, then wo)
  k_transpose_cvt<<<dim3(D_ / 32, D_ / 32), tb, 0, stream>>>(wq, wqkvt, D_, D_);
  k_transpose_cvt<<<dim3(32, D_ / 32), tb, 0, stream>>>(wk, wqkvt + (size_t)D_ * D_, D_, NKV_ * HD_);
  k_transpose_cvt<<<dim3(32, D_ / 32), tb, 0, stream>>>(wv, wqkvt + (size_t)(D_ + NKV_ * HD_) * D_, D_, NKV_ * HD_);
  k_transpose_cvt<<<dim3(D_ / 32, D_ / 32), tb, 0, stream>>>(wo, wot, D_, D_);
  // 3. fused QKV projection (grid 24x16 = 384 blocks, %8==0)
  k_gemm8p<bf16_t><<<dim3(NQK_ / 256, BS_ / 256), 512, 0, stream>>>(xb, wqkvt, qkv, BS_, NQK_, D_);
  // 4. RoPE + reorder (Q pre-scaled by 1/sqrt(HD)), V transpose
  k_rope<<<BS_ * NH_ * 64 / 256, 256, 0, stream>>>(qkv, fcos, fsin, qrope, NH_, 0, 0.08838834764831845f);
  k_rope<<<BS_ * NKV_ * 64 / 256, 256, 0, stream>>>(qkv, fcos, fsin, krope, NKV_, D_, 1.0f);
  k_vtrans<<<dim3(S_ / 32, HD_ / 32, B_ * NKV_), tb, 0, stream>>>(qkv, vtr);
  // 5. flash attention
  k_flash<<<dim3(S_ / 128, NH_, B_), 256, 0, stream>>>(qrope, krope, vtr, ctx);
  // 6. output projection -> f32 out (grid 16x16 = 256 blocks)
  k_gemm8p<float><<<dim3(D_ / 256, BS_ / 256), 512, 0, stream>>>(ctx, wot, out, BS_, D_, D_);
}

// Round 7
// 675.244 us; speedup vs baseline: 1.2263x; 1.0723x over previous
//
#include <hip/hip_runtime.h>
#include <hip/hip_bf16.h>
#include <cstdint>

#define B_   2
#define S_   2048
#define D_   4096
#define NH_  32
#define NKV_ 8
#define HD_  128
#define BS_  (B_*S_)      // 4096 rows
#define NQK_ 6144         // NH*HD + 2*NKV*HD

typedef __bf16 bf16_t;
typedef __bf16 bf16x8 __attribute__((ext_vector_type(8)));
typedef __bf16 bf16x4 __attribute__((ext_vector_type(4)));
typedef __bf16 bf16x2 __attribute__((ext_vector_type(2)));
typedef float  f32x4  __attribute__((ext_vector_type(4)));

typedef const __attribute__((address_space(1))) void* gas_ptr;
typedef __attribute__((address_space(3))) void* las_ptr;

__device__ __forceinline__ void gload_lds16(const void* g, void* l) {
  __builtin_amdgcn_global_load_lds((gas_ptr)g, (las_ptr)l, 16, 0, 0);
}

#define LD8(p) (*(const bf16x8*)(p))
#define MFMA(a, b, c) __builtin_amdgcn_mfma_f32_16x16x32_bf16(a, b, c, 0, 0, 0)

// ---------------- f32 -> bf16 convert (vectorized) ----------------
__global__ __launch_bounds__(256) void k_cvt(const float4* __restrict__ in,
                                             bf16x4* __restrict__ out, int n4) {
  int i = blockIdx.x * 256 + threadIdx.x;
  if (i >= n4) return;
  float4 v = in[i];
  bf16x4 o = { (bf16_t)v.x, (bf16_t)v.y, (bf16_t)v.z, (bf16_t)v.w };
  out[i] = o;
}

// ---------------- w[K][N] f32 -> wt[N][K] bf16 (tiled transpose) ----------------
__global__ __launch_bounds__(256) void k_transpose_cvt(const float* __restrict__ w,
                                                       bf16_t* __restrict__ wt,
                                                       int K, int N) {
  __shared__ float tile[32][33];
  int n0 = blockIdx.x * 32, k0 = blockIdx.y * 32;
  int tx = threadIdx.x, ty = threadIdx.y;   // 32x8
#pragma unroll
  for (int i = 0; i < 4; i++)
    tile[ty + 8*i][tx] = w[(size_t)(k0 + ty + 8*i) * N + n0 + tx];
  __syncthreads();
#pragma unroll
  for (int i = 0; i < 4; i++)
    wt[(size_t)(n0 + ty + 8*i) * K + k0 + tx] = (bf16_t)tile[tx][ty + 8*i];
}

// ---------------- 256x(64*NF) NT GEMM — 4-phase/K-tile template ----------------
// C[M][N] = A[M][K] @ Bt[N][K]^T. BK=64, 8 waves (2M x 4N), wave tile 128x16NF.
// NF=4: 256x256 tile (LDS 128KB); NF=3: 256x192 tile (LDS 112KB) -> lets gemm1
// (N=6144) launch 512 blocks = 2 CLEAN rounds on 256 CUs (round-6: 384-block
// grid = 1.5 rounds cost ~25% in tail; occupancy counter 17.4% proved it).
// Phases per K-tile (each: ds_reads+stage -> s_barrier -> lgkmcnt(0) -> setprio
// -> 4*NF MFMA -> barrier):
//   P0: b[NF]·kk0 + a[0..3]·kk0 ; stage A-half0(k+1)
//   P1: a[4..7]·kk0             ; stage A-half1(k+1)
//   P2: b[NF]·kk1 + a[0..3]·kk1
//   P3: a[4..7]·kk1 ; stage B(k+2) [NF loads] ; vmcnt(NF)
// vmcnt(NF) at P3 certifies A(k+1)+B(k+1) leaving only B(k+2) in flight (T4,
// never drains mid-loop). WAR: A-slots dbuf[(k+1)&1] freed at (k-1)P3 barrier;
// B-slots dbuf[k&1] freed at kP2's trailing barrier. Swizzle byte^=(row&7)<<4
// in 128B rows, both sides (verified conflict-free: round-4/6 counters = 0).
template <typename CT, int NF>
__global__ __launch_bounds__(512, 2) void k_gemm8p(const bf16_t* __restrict__ A,
                                                   const bf16_t* __restrict__ Bt,
                                                   CT* __restrict__ C,
                                                   int M, int N, int K) {
  __shared__ __align__(16) bf16_t As[2][256 * 64];       // 2 x 32 KB
  __shared__ __align__(16) bf16_t Bs[2][NF * 64 * 64];   // 2 x 8NF KB
  const int tid = threadIdx.x;
  const int l = tid & 63, w = tid >> 6;
  const int lr = l & 15, lg = l >> 4;
  const int wm = w >> 2, wn = w & 3;       // 2M x 4N wave grid

  // bm-fast plain indexing (round-5 measured lower FETCH than XCD-chunk here)
  const int bm = blockIdx.x, bn = blockIdx.y;

  const bf16_t* Ab = A  + (size_t)bm * 256 * K;
  const bf16_t* Bb = Bt + (size_t)bn * (NF * 64) * K;

  // staging map: thread's 16B slices; linear LDS dest, source col pre-swizzled
  int st_row[4], st_col[4], st_dst[4];
#pragma unroll
  for (int j = 0; j < 4; j++) {
    int o = (j * 512 + tid) * 16;          // byte offset
    int row = o >> 7, cb = o & 127;        // 128B rows
    st_row[j] = row;
    st_col[j] = (cb ^ ((row & 7) << 4)) >> 1;
    st_dst[j] = o >> 1;
  }

  // fragment read offsets (kk0; kk1 = ^32 elements)
  int aoff[8], boff[NF];
#pragma unroll
  for (int m = 0; m < 8; m++) {
    int r = wm * 128 + m * 16 + lr;
    aoff[m] = r * 64 + (((lg * 16) ^ ((r & 7) << 4)) >> 1);
  }
#pragma unroll
  for (int n = 0; n < NF; n++) {
    int r = wn * (16 * NF) + n * 16 + lr;
    boff[n] = r * 64 + (((lg * 16) ^ ((r & 7) << 4)) >> 1);
  }

  f32x4 acc[8][NF];
#pragma unroll
  for (int m = 0; m < 8; m++)
#pragma unroll
    for (int n = 0; n < NF; n++) acc[m][n] = f32x4{0.f, 0.f, 0.f, 0.f};

  auto stageA = [&](int k, int h) {       // half h: 128 rows, 2 loads
    const int kt = k << 6;
    const int rof = h << 7;
#pragma unroll
    for (int j = 0; j < 2; j++)
      gload_lds16(Ab + (size_t)(st_row[j] + rof) * K + kt + st_col[j],
                  &As[k & 1][0] + (rof << 6) + st_dst[j]);
  };
  auto stageB = [&](int k) {              // full B tile: 64NF rows, NF loads
    const int kt = k << 6;
#pragma unroll
    for (int j = 0; j < NF; j++)
      gload_lds16(Bb + (size_t)st_row[j] * K + kt + st_col[j],
                  &Bs[k & 1][0] + st_dst[j]);
  };

  const int NT = K >> 6;
  // prologue stream: A(0), B(0), B(1)
  stageA(0, 0); stageA(0, 1); stageB(0); stageB(1);
  if constexpr (NF == 3) asm volatile("s_waitcnt vmcnt(3)" ::: "memory");
  else                   asm volatile("s_waitcnt vmcnt(4)" ::: "memory");
  __builtin_amdgcn_s_barrier();

  for (int k = 0; k < NT; ++k) {
    const bf16_t* Ap = &As[k & 1][0];
    const bf16_t* Bp = &Bs[k & 1][0];
    const bool s1 = (k + 1 < NT), s2 = (k + 2 < NT);
    bf16x8 bfr[NF], a[4];

    // ---- P0: b kk0 + a[0..3] kk0 ; stage A-half0(k+1) ----
#pragma unroll
    for (int n = 0; n < NF; n++) bfr[n] = LD8(Bp + boff[n]);
#pragma unroll
    for (int m = 0; m < 4; m++) a[m] = LD8(Ap + aoff[m]);
    if (s1) stageA(k + 1, 0);
    __builtin_amdgcn_s_barrier();
    asm volatile("s_waitcnt lgkmcnt(0)" ::: "memory");
    __builtin_amdgcn_s_setprio(1);
#pragma unroll
    for (int m = 0; m < 4; m++)
#pragma unroll
      for (int n = 0; n < NF; n++)
        acc[m][n] = MFMA(a[m], bfr[n], acc[m][n]);
    __builtin_amdgcn_s_setprio(0);
    __builtin_amdgcn_s_barrier();

    // ---- P1: a[4..7] kk0 ; stage A-half1(k+1) ----
#pragma unroll
    for (int m = 0; m < 4; m++) a[m] = LD8(Ap + aoff[m + 4]);
    if (s1) stageA(k + 1, 1);
    __builtin_amdgcn_s_barrier();
    asm volatile("s_waitcnt lgkmcnt(0)" ::: "memory");
    __builtin_amdgcn_s_setprio(1);
#pragma unroll
    for (int m = 0; m < 4; m++)
#pragma unroll
      for (int n = 0; n < NF; n++)
        acc[m + 4][n] = MFMA(a[m], bfr[n], acc[m + 4][n]);
    __builtin_amdgcn_s_setprio(0);
    __builtin_amdgcn_s_barrier();

    // ---- P2: b kk1 + a[0..3] kk1 ----
#pragma unroll
    for (int n = 0; n < NF; n++) bfr[n] = LD8(Bp + (boff[n] ^ 32));
#pragma unroll
    for (int m = 0; m < 4; m++) a[m] = LD8(Ap + (aoff[m] ^ 32));
    __builtin_amdgcn_s_barrier();
    asm volatile("s_waitcnt lgkmcnt(0)" ::: "memory");
    __builtin_amdgcn_s_setprio(1);
#pragma unroll
    for (int m = 0; m < 4; m++)
#pragma unroll
      for (int n = 0; n < NF; n++)
        acc[m][n] = MFMA(a[m], bfr[n], acc[m][n]);
    __builtin_amdgcn_s_setprio(0);
    __builtin_amdgcn_s_barrier();

    // ---- P3: a[4..7] kk1 ; stage B(k+2) ; boundary vmcnt ----
#pragma unroll
    for (int m = 0; m < 4; m++) a[m] = LD8(Ap + (aoff[m + 4] ^ 32));
    if (s2) {
      stageB(k + 2);
      if constexpr (NF == 3) asm volatile("s_waitcnt vmcnt(3)" ::: "memory");
      else                   asm volatile("s_waitcnt vmcnt(4)" ::: "memory");
    } else if (s1) {
      asm volatile("s_waitcnt vmcnt(0)" ::: "memory");
    }
    __builtin_amdgcn_s_barrier();
    asm volatile("s_waitcnt lgkmcnt(0)" ::: "memory");
    __builtin_amdgcn_s_setprio(1);
#pragma unroll
    for (int m = 0; m < 4; m++)
#pragma unroll
      for (int n = 0; n < NF; n++)
        acc[m + 4][n] = MFMA(a[m], bfr[n], acc[m + 4][n]);
    __builtin_amdgcn_s_setprio(0);
    __builtin_amdgcn_s_barrier();
  }

#pragma unroll
  for (int m = 0; m < 8; m++) {
    int row0 = bm * 256 + wm * 128 + m * 16 + lg * 4;
#pragma unroll
    for (int n = 0; n < NF; n++) {
      int col = bn * (NF * 64) + wn * (16 * NF) + n * 16 + lr;
#pragma unroll
      for (int i = 0; i < 4; i++)
        C[(size_t)(row0 + i) * N + col] = (CT)acc[m][n][i];
    }
  }
}

// ---------------- RoPE + head-major reorder ----------------
__global__ __launch_bounds__(256) void k_rope(const bf16_t* __restrict__ qkv,
                                              const float* __restrict__ fcos,
                                              const float* __restrict__ fsin,
                                              bf16_t* __restrict__ dst,
                                              int nheads, int col_off, float mul) {
  int idx = blockIdx.x * 256 + threadIdx.x;   // B*S*nheads*64 threads
  int p = idx & 63;
  int h = (idx >> 6) % nheads;
  int bs = idx / (64 * nheads);
  int s = bs & (S_ - 1);
  int b = bs >> 11;                            // bs / S_
  const bf16_t* src = qkv + (size_t)bs * NQK_ + col_off + h * HD_ + 2 * p;
  bf16x2 ab = *(const bf16x2*)src;
  float a = (float)ab[0], bb = (float)ab[1];
  float c = fcos[s * 64 + p], sn = fsin[s * 64 + p];
  bf16x2 o = { (bf16_t)((a * c - bb * sn) * mul), (bf16_t)((a * sn + bb * c) * mul) };
  *(bf16x2*)(dst + ((((size_t)b * nheads + h) * S_ + s) * HD_) + 2 * p) = o;
}

// ---------------- V transpose: qkv v-cols -> vt[B][NKV][HD][S] ----------------
__global__ __launch_bounds__(256) void k_vtrans(const bf16_t* __restrict__ qkv,
                                                bf16_t* __restrict__ vtr) {
  __shared__ bf16_t tile[32][33];
  int s0 = blockIdx.x * 32, d0 = blockIdx.y * 32, z = blockIdx.z;  // z = b*NKV+kvh
  int b = z >> 3, kvh = z & 7;
  int tx = threadIdx.x, ty = threadIdx.y;
#pragma unroll
  for (int i = 0; i < 4; i++)
    tile[ty + 8*i][tx] =
        qkv[(size_t)(b * S_ + s0 + ty + 8*i) * NQK_ + (D_ + NKV_ * HD_) + kvh * HD_ + d0 + tx];
  __syncthreads();
#pragma unroll
  for (int i = 0; i < 4; i++)
    vtr[((size_t)z * HD_ + d0 + ty + 8*i) * S_ + s0 + tx] = tile[tx][ty + 8*i];
}

// ---------------- Flash attention (non-causal, GQA) ----------------
// grid (S/128, NH, B), 256 thr (4 waves). Wave w owns q rows [qb*128+w*32, +32)
// as two 16-row m-frags. K/V tiles (KVBLK=64) LDS double-buffered, XOR-swizzled.
// P scratch: swizzled 128B rows (byte^=(row&7)<<4 both sides) -> b128 P-read
// conflict-free (old 144B-row layout was 8-way: round-6 counters 1.05e7).
// Defer-max (T13, THR=8): skip O-rescale while per-tile max growth <= 8.
#define KVBLK 64
__global__ __launch_bounds__(256, 2) void k_flash(const bf16_t* __restrict__ qr,
                                                  const bf16_t* __restrict__ kr,
                                                  const bf16_t* __restrict__ vt,
                                                  bf16_t* __restrict__ ctx) {
  __shared__ __align__(16) bf16_t Ks[2][KVBLK * HD_];   // 2 x 16 KB [row s][col d]
  __shared__ __align__(16) bf16_t Vs[2][HD_ * KVBLK];   // 2 x 16 KB [row d][col s]
  __shared__ __align__(16) char  plds[4][2048];         // per-wave P: 16 x 128B swz
  const int tid = threadIdx.x;
  const int l = tid & 63, w = tid >> 6;
  const int lr = l & 15, lg = l >> 4;
  const int qb = blockIdx.x, h = blockIdx.y, b = blockIdx.z;
  const int kvh = h >> 2;   // NREP=4

  const bf16_t* qbase = qr + (((size_t)b * NH_ + h) * S_ + qb * 128 + w * 32) * HD_;
  const bf16_t* kbase = kr + (((size_t)b * NKV_ + kvh) * S_) * HD_;
  const bf16_t* vbase = vt + (((size_t)b * NKV_ + kvh) * HD_) * S_;

  // Q fragments (pre-scaled by 1/sqrt(HD) in k_rope)
  bf16x8 qf[2][4];
#pragma unroll
  for (int m = 0; m < 2; m++)
#pragma unroll
    for (int kk = 0; kk < 4; kk++)
      qf[m][kk] = *(const bf16x8*)(qbase + (m * 16 + lr) * HD_ + kk * 32 + lg * 8);

  f32x4 o[2][8];
#pragma unroll
  for (int m = 0; m < 2; m++)
#pragma unroll
    for (int n = 0; n < 8; n++) o[m][n] = f32x4{0.f, 0.f, 0.f, 0.f};
  float mR[2][4], lR[2][4];
#pragma unroll
  for (int m = 0; m < 2; m++)
#pragma unroll
    for (int i = 0; i < 4; i++) { mR[m][i] = -1e30f; lR[m][i] = 0.f; }

  // stage tile t into buffer bu (K: 16KB, V: 16KB; 8 gload16/thread)
  auto stage = [&](int bu, int t) {
    const int kb = t * KVBLK;
#pragma unroll
    for (int j = 0; j < 4; j++) {
      int o_ = (tid + 256 * j) * 16;                 // byte offset in K tile
      int row = o_ >> 8, cb = o_ & 255;              // row stride 256B
      int scb = cb ^ ((row & 7) << 4);
      gload_lds16(kbase + (size_t)(kb + row) * HD_ + (scb >> 1),
                  &Ks[bu][0] + (o_ >> 1));
    }
#pragma unroll
    for (int j = 0; j < 4; j++) {
      int o_ = (tid + 256 * j) * 16;                 // byte offset in V tile
      int row = o_ >> 7, cb = o_ & 127;              // row stride 128B
      int scb = cb ^ ((row & 7) << 4);
      gload_lds16(vbase + (size_t)row * S_ + kb + (scb >> 1),
                  &Vs[bu][0] + (o_ >> 1));
    }
  };

  const int nt = S_ / KVBLK;
  stage(0, 0);
  __syncthreads();
  int buf = 0;

  for (int t = 0; t < nt; t++) {
    if (t + 1 < nt) stage(buf ^ 1, t + 1);
    const bf16_t* Kb = &Ks[buf][0];
    const bf16_t* Vb = &Vs[buf][0];

    // QK^T: sc[m][n], K frag shared across m
    f32x4 sc[2][4];
#pragma unroll
    for (int m = 0; m < 2; m++)
#pragma unroll
      for (int n = 0; n < 4; n++) sc[m][n] = f32x4{0.f, 0.f, 0.f, 0.f};
    __builtin_amdgcn_s_setprio(1);
#pragma unroll
    for (int n = 0; n < 4; n++) {
#pragma unroll
      for (int kk = 0; kk < 4; kk++) {
        int r = n * 16 + lr;
        int cb = (kk * 64 + lg * 16) ^ ((r & 7) << 4);
        bf16x8 kf = *(const bf16x8*)(Kb + (((r << 8) + cb) >> 1));
        sc[0][n] = MFMA(qf[0][kk], kf, sc[0][n]);
        sc[1][n] = MFMA(qf[1][kk], kf, sc[1][n]);
      }
    }
    __builtin_amdgcn_s_setprio(0);

    // online softmax per m-frag (defer-max); P via swizzled per-wave LDS
    bf16x8 pf[2][2];
#pragma unroll
    for (int m = 0; m < 2; m++) {
      float tmax[4];
#pragma unroll
      for (int i = 0; i < 4; i++) {
        float tmx = fmaxf(fmaxf(sc[m][0][i], sc[m][1][i]),
                          fmaxf(sc[m][2][i], sc[m][3][i]));
        tmx = fmaxf(tmx, __shfl_xor(tmx, 1));
        tmx = fmaxf(tmx, __shfl_xor(tmx, 2));
        tmx = fmaxf(tmx, __shfl_xor(tmx, 4));
        tmx = fmaxf(tmx, __shfl_xor(tmx, 8));
        tmax[i] = tmx;
      }
      float need = tmax[0] - mR[m][0];
#pragma unroll
      for (int i = 1; i < 4; i++) need = fmaxf(need, tmax[i] - mR[m][i]);
      if (!__all(need <= 8.0f)) {          // rare after first tile
        float alpha[4];
#pragma unroll
        for (int i = 0; i < 4; i++) {
          float mnew = fmaxf(mR[m][i], tmax[i]);
          alpha[i] = __expf(mR[m][i] - mnew);
          mR[m][i] = mnew;
          lR[m][i] *= alpha[i];
        }
#pragma unroll
        for (int n = 0; n < 8; n++)
#pragma unroll
          for (int i = 0; i < 4; i++) o[m][n][i] *= alpha[i];
      }
      float psum[4] = {0.f, 0.f, 0.f, 0.f};
#pragma unroll
      for (int n = 0; n < 4; n++)
#pragma unroll
        for (int i = 0; i < 4; i++) {
          float pv = __expf(sc[m][n][i] - mR[m][i]);   // bounded by e^8
          psum[i] += pv;
          int r = lg * 4 + i;
          int cbyte = (n * 32 + lr * 2) ^ ((r & 7) << 4);
          *(bf16_t*)(&plds[w][r * 128 + cbyte]) = (bf16_t)pv;
        }
#pragma unroll
      for (int i = 0; i < 4; i++) {
        float t2 = psum[i];
        t2 += __shfl_xor(t2, 1);
        t2 += __shfl_xor(t2, 2);
        t2 += __shfl_xor(t2, 4);
        t2 += __shfl_xor(t2, 8);
        lR[m][i] += t2;
      }
      pf[m][0] = *(const bf16x8*)(&plds[w][lr * 128 + ((lg * 16) ^ ((lr & 7) << 4))]);
      pf[m][1] = *(const bf16x8*)(&plds[w][lr * 128 + ((64 + lg * 16) ^ ((lr & 7) << 4))]);
    }

    // PV: V frag loaded once, shared across both m
    __builtin_amdgcn_s_setprio(1);
#pragma unroll
    for (int n = 0; n < 8; n++) {
#pragma unroll
      for (int kk = 0; kk < 2; kk++) {
        int r = n * 16 + lr;
        int cb = (kk * 64 + lg * 16) ^ ((r & 7) << 4);
        bf16x8 vf = *(const bf16x8*)(Vb + (((r << 7) + cb) >> 1));
        o[0][n] = MFMA(pf[0][kk], vf, o[0][n]);
        o[1][n] = MFMA(pf[1][kk], vf, o[1][n]);
      }
    }
    __builtin_amdgcn_s_setprio(0);
    __syncthreads();
    buf ^= 1;
  }

#pragma unroll
  for (int m = 0; m < 2; m++)
#pragma unroll
    for (int n = 0; n < 8; n++)
#pragma unroll
      for (int i = 0; i < 4; i++) {
        int srow = qb * 128 + w * 32 + m * 16 + lg * 4 + i;
        int d = n * 16 + lr;
        ctx[((size_t)(b * S_ + srow)) * D_ + h * HD_ + d] = (bf16_t)(o[m][n][i] / lR[m][i]);
      }
}

// ---------------- launch ----------------
extern "C" void kernel_launch(void* const* d_in, const int* in_sizes, int n_in,
                              void* d_out, int out_size, void* d_ws, size_t ws_size,
                              hipStream_t stream) {
  const float* x    = (const float*)d_in[0];
  const float* wq   = (const float*)d_in[1];
  const float* wk   = (const float*)d_in[2];
  const float* wv   = (const float*)d_in[3];
  const float* wo   = (const float*)d_in[4];
  const float* fcos = (const float*)d_in[5];
  const float* fsin = (const float*)d_in[6];
  float* out = (float*)d_out;

  // workspace layout (aliased; 160 MB total)
  const size_t SZ_XB    = (size_t)BS_ * D_ * 2;      // 32 MB  (xb, later qrope)
  const size_t SZ_WQKVT = (size_t)NQK_ * D_ * 2;     // 48 MB  (wqkvt, later krope+vtr)
  const size_t SZ_WOT   = (size_t)D_ * D_ * 2;       // 32 MB
  char* p = (char*)d_ws;
  bf16_t* xb    = (bf16_t*)p;                        // then qrope
  bf16_t* wqkvt = (bf16_t*)(p + SZ_XB);              // then krope, vtr
  bf16_t* wot   = (bf16_t*)(p + SZ_XB + SZ_WQKVT);
  bf16_t* qkv   = (bf16_t*)(p + SZ_XB + SZ_WQKVT + SZ_WOT);  // then ctx
  bf16_t* qrope = xb;
  bf16_t* krope = wqkvt;
  bf16_t* vtr   = wqkvt + (size_t)BS_ * NKV_ * HD_;
  bf16_t* ctx   = qkv;

  dim3 tb(32, 8);
  // 1. x -> bf16
  k_cvt<<<BS_ * D_ / 1024, 256, 0, stream>>>((const float4*)x, (bf16x4*)xb, BS_ * D_ / 4);
  // 2. transpose+convert weights (fused qkv weight, then wo)
  k_transpose_cvt<<<dim3(D_ / 32, D_ / 32), tb, 0, stream>>>(wq, wqkvt, D_, D_);
  k_transpose_cvt<<<dim3(32, D_ / 32), tb, 0, stream>>>(wk, wqkvt + (size_t)D_ * D_, D_, NKV_ * HD_);
  k_transpose_cvt<<<dim3(32, D_ / 32), tb, 0, stream>>>(wv, wqkvt + (size_t)(D_ + NKV_ * HD_) * D_, D_, NKV_ * HD_);
  k_transpose_cvt<<<dim3(D_ / 32, D_ / 32), tb, 0, stream>>>(wo, wot, D_, D_);
  // 3. fused QKV projection: 256x192 tiles -> grid 16x32 = 512 = 2 clean rounds
  k_gemm8p<bf16_t, 3><<<dim3(BS_ / 256, NQK_ / 192), 512, 0, stream>>>(xb, wqkvt, qkv, BS_, NQK_, D_);
  // 4. RoPE + reorder (Q pre-scaled by 1/sqrt(HD)), V transpose
  k_rope<<<BS_ * NH_ * 64 / 256, 256, 0, stream>>>(qkv, fcos, fsin, qrope, NH_, 0, 0.08838834764831845f);
  k_rope<<<BS_ * NKV_ * 64 / 256, 256, 0, stream>>>(qkv, fcos, fsin, krope, NKV_, D_, 1.0f);
  k_vtrans<<<dim3(S_ / 32, HD_ / 32, B_ * NKV_), tb, 0, stream>>>(qkv, vtr);
  // 5. flash attention
  k_flash<<<dim3(S_ / 128, NH_, B_), 256, 0, stream>>>(qrope, krope, vtr, ctx);
  // 6. output projection -> f32 out: 256x256 tiles, grid 16x16 = 256 = 1 round
  k_gemm8p<float, 4><<<dim3(BS_ / 256, D_ / 256), 512, 0, stream>>>(ctx, wot, out, BS_, D_, D_);
}

// Round 8
// 606.702 us; speedup vs baseline: 1.3648x; 1.1130x over previous
//
#include <hip/hip_runtime.h>
#include <hip/hip_bf16.h>
#include <cstdint>

#define B_   2
#define S_   2048
#define D_   4096
#define NH_  32
#define NKV_ 8
#define HD_  128
#define BS_  (B_*S_)      // 4096 rows
#define NQK_ 6144         // NH*HD + 2*NKV*HD

typedef __bf16 bf16_t;
typedef __bf16 bf16x8 __attribute__((ext_vector_type(8)));
typedef __bf16 bf16x4 __attribute__((ext_vector_type(4)));
typedef __bf16 bf16x2 __attribute__((ext_vector_type(2)));
typedef float  f32x4  __attribute__((ext_vector_type(4)));

typedef const __attribute__((address_space(1))) void* gas_ptr;
typedef __attribute__((address_space(3))) void* las_ptr;

__device__ __forceinline__ void gload_lds16(const void* g, void* l) {
  __builtin_amdgcn_global_load_lds((gas_ptr)g, (las_ptr)l, 16, 0, 0);
}

__device__ __forceinline__ float exp2_fast(float x) {   // v_exp_f32 = 2^x
  float r;
  asm("v_exp_f32 %0, %1" : "=v"(r) : "v"(x));
  return r;
}

#define LD8(p) (*(const bf16x8*)(p))
#define MFMA(a, b, c) __builtin_amdgcn_mfma_f32_16x16x32_bf16(a, b, c, 0, 0, 0)

// ---------------- f32 -> bf16 convert (vectorized) ----------------
__global__ __launch_bounds__(256) void k_cvt(const float4* __restrict__ in,
                                             bf16x4* __restrict__ out, int n4) {
  int i = blockIdx.x * 256 + threadIdx.x;
  if (i >= n4) return;
  float4 v = in[i];
  bf16x4 o = { (bf16_t)v.x, (bf16_t)v.y, (bf16_t)v.z, (bf16_t)v.w };
  out[i] = o;
}

// ---------------- w[K][N] f32 -> wt[N][K] bf16 (tiled transpose) ----------------
__global__ __launch_bounds__(256) void k_transpose_cvt(const float* __restrict__ w,
                                                       bf16_t* __restrict__ wt,
                                                       int K, int N) {
  __shared__ float tile[32][33];
  int n0 = blockIdx.x * 32, k0 = blockIdx.y * 32;
  int tx = threadIdx.x, ty = threadIdx.y;   // 32x8
#pragma unroll
  for (int i = 0; i < 4; i++)
    tile[ty + 8*i][tx] = w[(size_t)(k0 + ty + 8*i) * N + n0 + tx];
  __syncthreads();
#pragma unroll
  for (int i = 0; i < 4; i++)
    wt[(size_t)(n0 + ty + 8*i) * K + k0 + tx] = (bf16_t)tile[tx][ty + 8*i];
}

// ---------------- 256x(64*NF) NT GEMM — 4-phase/K-tile template ----------------
// (unchanged from round 7; see comments there. NF=3 for gemm1 -> 512 blocks = 2
// clean rounds; NF=4 for gemm2 -> 256 blocks = 1 round.)
template <typename CT, int NF>
__global__ __launch_bounds__(512, 2) void k_gemm8p(const bf16_t* __restrict__ A,
                                                   const bf16_t* __restrict__ Bt,
                                                   CT* __restrict__ C,
                                                   int M, int N, int K) {
  __shared__ __align__(16) bf16_t As[2][256 * 64];       // 2 x 32 KB
  __shared__ __align__(16) bf16_t Bs[2][NF * 64 * 64];   // 2 x 8NF KB
  const int tid = threadIdx.x;
  const int l = tid & 63, w = tid >> 6;
  const int lr = l & 15, lg = l >> 4;
  const int wm = w >> 2, wn = w & 3;       // 2M x 4N wave grid

  const int bm = blockIdx.x, bn = blockIdx.y;

  const bf16_t* Ab = A  + (size_t)bm * 256 * K;
  const bf16_t* Bb = Bt + (size_t)bn * (NF * 64) * K;

  int st_row[4], st_col[4], st_dst[4];
#pragma unroll
  for (int j = 0; j < 4; j++) {
    int o = (j * 512 + tid) * 16;          // byte offset
    int row = o >> 7, cb = o & 127;        // 128B rows
    st_row[j] = row;
    st_col[j] = (cb ^ ((row & 7) << 4)) >> 1;
    st_dst[j] = o >> 1;
  }

  int aoff[8], boff[NF];
#pragma unroll
  for (int m = 0; m < 8; m++) {
    int r = wm * 128 + m * 16 + lr;
    aoff[m] = r * 64 + (((lg * 16) ^ ((r & 7) << 4)) >> 1);
  }
#pragma unroll
  for (int n = 0; n < NF; n++) {
    int r = wn * (16 * NF) + n * 16 + lr;
    boff[n] = r * 64 + (((lg * 16) ^ ((r & 7) << 4)) >> 1);
  }

  f32x4 acc[8][NF];
#pragma unroll
  for (int m = 0; m < 8; m++)
#pragma unroll
    for (int n = 0; n < NF; n++) acc[m][n] = f32x4{0.f, 0.f, 0.f, 0.f};

  auto stageA = [&](int k, int h) {       // half h: 128 rows, 2 loads
    const int kt = k << 6;
    const int rof = h << 7;
#pragma unroll
    for (int j = 0; j < 2; j++)
      gload_lds16(Ab + (size_t)(st_row[j] + rof) * K + kt + st_col[j],
                  &As[k & 1][0] + (rof << 6) + st_dst[j]);
  };
  auto stageB = [&](int k) {              // full B tile: 64NF rows, NF loads
    const int kt = k << 6;
#pragma unroll
    for (int j = 0; j < NF; j++)
      gload_lds16(Bb + (size_t)st_row[j] * K + kt + st_col[j],
                  &Bs[k & 1][0] + st_dst[j]);
  };

  const int NT = K >> 6;
  stageA(0, 0); stageA(0, 1); stageB(0); stageB(1);
  if constexpr (NF == 3) asm volatile("s_waitcnt vmcnt(3)" ::: "memory");
  else                   asm volatile("s_waitcnt vmcnt(4)" ::: "memory");
  __builtin_amdgcn_s_barrier();

  for (int k = 0; k < NT; ++k) {
    const bf16_t* Ap = &As[k & 1][0];
    const bf16_t* Bp = &Bs[k & 1][0];
    const bool s1 = (k + 1 < NT), s2 = (k + 2 < NT);
    bf16x8 bfr[NF], a[4];

    // ---- P0: b kk0 + a[0..3] kk0 ; stage A-half0(k+1) ----
#pragma unroll
    for (int n = 0; n < NF; n++) bfr[n] = LD8(Bp + boff[n]);
#pragma unroll
    for (int m = 0; m < 4; m++) a[m] = LD8(Ap + aoff[m]);
    if (s1) stageA(k + 1, 0);
    __builtin_amdgcn_s_barrier();
    asm volatile("s_waitcnt lgkmcnt(0)" ::: "memory");
    __builtin_amdgcn_s_setprio(1);
#pragma unroll
    for (int m = 0; m < 4; m++)
#pragma unroll
      for (int n = 0; n < NF; n++)
        acc[m][n] = MFMA(a[m], bfr[n], acc[m][n]);
    __builtin_amdgcn_s_setprio(0);
    __builtin_amdgcn_s_barrier();

    // ---- P1: a[4..7] kk0 ; stage A-half1(k+1) ----
#pragma unroll
    for (int m = 0; m < 4; m++) a[m] = LD8(Ap + aoff[m + 4]);
    if (s1) stageA(k + 1, 1);
    __builtin_amdgcn_s_barrier();
    asm volatile("s_waitcnt lgkmcnt(0)" ::: "memory");
    __builtin_amdgcn_s_setprio(1);
#pragma unroll
    for (int m = 0; m < 4; m++)
#pragma unroll
      for (int n = 0; n < NF; n++)
        acc[m + 4][n] = MFMA(a[m], bfr[n], acc[m + 4][n]);
    __builtin_amdgcn_s_setprio(0);
    __builtin_amdgcn_s_barrier();

    // ---- P2: b kk1 + a[0..3] kk1 ----
#pragma unroll
    for (int n = 0; n < NF; n++) bfr[n] = LD8(Bp + (boff[n] ^ 32));
#pragma unroll
    for (int m = 0; m < 4; m++) a[m] = LD8(Ap + (aoff[m] ^ 32));
    __builtin_amdgcn_s_barrier();
    asm volatile("s_waitcnt lgkmcnt(0)" ::: "memory");
    __builtin_amdgcn_s_setprio(1);
#pragma unroll
    for (int m = 0; m < 4; m++)
#pragma unroll
      for (int n = 0; n < NF; n++)
        acc[m][n] = MFMA(a[m], bfr[n], acc[m][n]);
    __builtin_amdgcn_s_setprio(0);
    __builtin_amdgcn_s_barrier();

    // ---- P3: a[4..7] kk1 ; stage B(k+2) ; boundary vmcnt ----
#pragma unroll
    for (int m = 0; m < 4; m++) a[m] = LD8(Ap + (aoff[m + 4] ^ 32));
    if (s2) {
      stageB(k + 2);
      if constexpr (NF == 3) asm volatile("s_waitcnt vmcnt(3)" ::: "memory");
      else                   asm volatile("s_waitcnt vmcnt(4)" ::: "memory");
    } else if (s1) {
      asm volatile("s_waitcnt vmcnt(0)" ::: "memory");
    }
    __builtin_amdgcn_s_barrier();
    asm volatile("s_waitcnt lgkmcnt(0)" ::: "memory");
    __builtin_amdgcn_s_setprio(1);
#pragma unroll
    for (int m = 0; m < 4; m++)
#pragma unroll
      for (int n = 0; n < NF; n++)
        acc[m + 4][n] = MFMA(a[m], bfr[n], acc[m + 4][n]);
    __builtin_amdgcn_s_setprio(0);
    __builtin_amdgcn_s_barrier();
  }

#pragma unroll
  for (int m = 0; m < 8; m++) {
    int row0 = bm * 256 + wm * 128 + m * 16 + lg * 4;
#pragma unroll
    for (int n = 0; n < NF; n++) {
      int col = bn * (NF * 64) + wn * (16 * NF) + n * 16 + lr;
#pragma unroll
      for (int i = 0; i < 4; i++)
        C[(size_t)(row0 + i) * N + col] = (CT)acc[m][n][i];
    }
  }
}

// ---------------- RoPE + head-major reorder ----------------
__global__ __launch_bounds__(256) void k_rope(const bf16_t* __restrict__ qkv,
                                              const float* __restrict__ fcos,
                                              const float* __restrict__ fsin,
                                              bf16_t* __restrict__ dst,
                                              int nheads, int col_off, float mul) {
  int idx = blockIdx.x * 256 + threadIdx.x;   // B*S*nheads*64 threads
  int p = idx & 63;
  int h = (idx >> 6) % nheads;
  int bs = idx / (64 * nheads);
  int s = bs & (S_ - 1);
  int b = bs >> 11;                            // bs / S_
  const bf16_t* src = qkv + (size_t)bs * NQK_ + col_off + h * HD_ + 2 * p;
  bf16x2 ab = *(const bf16x2*)src;
  float a = (float)ab[0], bb = (float)ab[1];
  float c = fcos[s * 64 + p], sn = fsin[s * 64 + p];
  bf16x2 o = { (bf16_t)((a * c - bb * sn) * mul), (bf16_t)((a * sn + bb * c) * mul) };
  *(bf16x2*)(dst + ((((size_t)b * nheads + h) * S_ + s) * HD_) + 2 * p) = o;
}

// ---------------- V transpose: qkv v-cols -> vt[B][NKV][HD][S] ----------------
__global__ __launch_bounds__(256) void k_vtrans(const bf16_t* __restrict__ qkv,
                                                bf16_t* __restrict__ vtr) {
  __shared__ bf16_t tile[32][33];
  int s0 = blockIdx.x * 32, d0 = blockIdx.y * 32, z = blockIdx.z;  // z = b*NKV+kvh
  int b = z >> 3, kvh = z & 7;
  int tx = threadIdx.x, ty = threadIdx.y;
#pragma unroll
  for (int i = 0; i < 4; i++)
    tile[ty + 8*i][tx] =
        qkv[(size_t)(b * S_ + s0 + ty + 8*i) * NQK_ + (D_ + NKV_ * HD_) + kvh * HD_ + d0 + tx];
  __syncthreads();
#pragma unroll
  for (int i = 0; i < 4; i++)
    vtr[((size_t)z * HD_ + d0 + ty + 8*i) * S_ + s0 + tx] = tile[tx][ty + 8*i];
}

// ---------------- Flash attention (non-causal, GQA) ----------------
// grid (S/128, NH, B), 256 thr (4 waves). Wave w owns q rows [qb*128+w*32, +32)
// as two 16-row m-frags. K/V tiles (KVBLK=64) LDS double-buffered, XOR-swizzled.
// Scores are in LOG2 domain (Q pre-scaled by log2e/sqrt(HD)) -> pv = v_exp_f32.
// Defer-max (T13): per-lane overflow check only (__all, no shuffles); full
// shuffle row-max reduce + O-rescale only on trigger (tile 0 + rare growth).
// Row-sum via ones-column MFMA: o[m][8] accumulates P·1 on the matrix pipe ->
// no psum adds / bpermutes; lR = o[m][8][i] and rescales uniformly with O.
#define KVBLK 64
#define SM_THR 12.0f     // log2-domain defer threshold (P bounded by 2^12)
__global__ __launch_bounds__(256, 2) void k_flash(const bf16_t* __restrict__ qr,
                                                  const bf16_t* __restrict__ kr,
                                                  const bf16_t* __restrict__ vt,
                                                  bf16_t* __restrict__ ctx) {
  __shared__ __align__(16) bf16_t Ks[2][KVBLK * HD_];   // 2 x 16 KB [row s][col d]
  __shared__ __align__(16) bf16_t Vs[2][HD_ * KVBLK];   // 2 x 16 KB [row d][col s]
  __shared__ __align__(16) char  plds[4][2048];         // per-wave P: 16 x 128B swz
  const int tid = threadIdx.x;
  const int l = tid & 63, w = tid >> 6;
  const int lr = l & 15, lg = l >> 4;
  const int qb = blockIdx.x, h = blockIdx.y, b = blockIdx.z;
  const int kvh = h >> 2;   // NREP=4

  const bf16_t* qbase = qr + (((size_t)b * NH_ + h) * S_ + qb * 128 + w * 32) * HD_;
  const bf16_t* kbase = kr + (((size_t)b * NKV_ + kvh) * S_) * HD_;
  const bf16_t* vbase = vt + (((size_t)b * NKV_ + kvh) * HD_) * S_;

  // Q fragments (pre-scaled by log2e/sqrt(HD) in k_rope)
  bf16x8 qf[2][4];
#pragma unroll
  for (int m = 0; m < 2; m++)
#pragma unroll
    for (int kk = 0; kk < 4; kk++)
      qf[m][kk] = *(const bf16x8*)(qbase + (m * 16 + lr) * HD_ + kk * 32 + lg * 8);

  bf16x8 ones;
#pragma unroll
  for (int j = 0; j < 8; j++) ones[j] = (bf16_t)1.0f;

  f32x4 o[2][9];                     // [..][8] = row-sum accumulator
#pragma unroll
  for (int m = 0; m < 2; m++)
#pragma unroll
    for (int n = 0; n < 9; n++) o[m][n] = f32x4{0.f, 0.f, 0.f, 0.f};
  float mR[2][4];
#pragma unroll
  for (int m = 0; m < 2; m++)
#pragma unroll
    for (int i = 0; i < 4; i++) mR[m][i] = -1e30f;

  // stage tile t into buffer bu (K: 16KB, V: 16KB; 8 gload16/thread)
  auto stage = [&](int bu, int t) {
    const int kb = t * KVBLK;
#pragma unroll
    for (int j = 0; j < 4; j++) {
      int o_ = (tid + 256 * j) * 16;                 // byte offset in K tile
      int row = o_ >> 8, cb = o_ & 255;              // row stride 256B
      int scb = cb ^ ((row & 7) << 4);
      gload_lds16(kbase + (size_t)(kb + row) * HD_ + (scb >> 1),
                  &Ks[bu][0] + (o_ >> 1));
    }
#pragma unroll
    for (int j = 0; j < 4; j++) {
      int o_ = (tid + 256 * j) * 16;                 // byte offset in V tile
      int row = o_ >> 7, cb = o_ & 127;              // row stride 128B
      int scb = cb ^ ((row & 7) << 4);
      gload_lds16(vbase + (size_t)row * S_ + kb + (scb >> 1),
                  &Vs[bu][0] + (o_ >> 1));
    }
  };

  const int nt = S_ / KVBLK;
  stage(0, 0);
  __syncthreads();
  int buf = 0;

  for (int t = 0; t < nt; t++) {
    if (t + 1 < nt) stage(buf ^ 1, t + 1);
    const bf16_t* Kb = &Ks[buf][0];
    const bf16_t* Vb = &Vs[buf][0];

    // QK^T: sc[m][n] (log2 domain), K frag shared across m
    f32x4 sc[2][4];
#pragma unroll
    for (int m = 0; m < 2; m++)
#pragma unroll
      for (int n = 0; n < 4; n++) sc[m][n] = f32x4{0.f, 0.f, 0.f, 0.f};
    __builtin_amdgcn_s_setprio(1);
#pragma unroll
    for (int n = 0; n < 4; n++) {
#pragma unroll
      for (int kk = 0; kk < 4; kk++) {
        int r = n * 16 + lr;
        int cb = (kk * 64 + lg * 16) ^ ((r & 7) << 4);
        bf16x8 kf = *(const bf16x8*)(Kb + (((r << 8) + cb) >> 1));
        sc[0][n] = MFMA(qf[0][kk], kf, sc[0][n]);
        sc[1][n] = MFMA(qf[1][kk], kf, sc[1][n]);
      }
    }
    __builtin_amdgcn_s_setprio(0);

    // softmax per m-frag: lane-local overflow check, rare full rescale
    bf16x8 pf[2][2];
#pragma unroll
    for (int m = 0; m < 2; m++) {
      float chk = -1e30f;
#pragma unroll
      for (int i = 0; i < 4; i++) {
        float lm = fmaxf(fmaxf(sc[m][0][i], sc[m][1][i]),
                         fmaxf(sc[m][2][i], sc[m][3][i]));
        chk = fmaxf(chk, lm - mR[m][i]);
      }
      if (!__all(chk <= SM_THR)) {     // trigger: tile 0 + rare max growth
#pragma unroll
        for (int i = 0; i < 4; i++) {
          float tmx = fmaxf(fmaxf(sc[m][0][i], sc[m][1][i]),
                            fmaxf(sc[m][2][i], sc[m][3][i]));
          tmx = fmaxf(tmx, __shfl_xor(tmx, 1));
          tmx = fmaxf(tmx, __shfl_xor(tmx, 2));
          tmx = fmaxf(tmx, __shfl_xor(tmx, 4));
          tmx = fmaxf(tmx, __shfl_xor(tmx, 8));
          float mnew = fmaxf(mR[m][i], tmx);
          float alpha = exp2_fast(mR[m][i] - mnew);
          mR[m][i] = mnew;
#pragma unroll
          for (int n = 0; n < 9; n++) o[m][n][i] *= alpha;
        }
      }
      // P = 2^(sc - mR), written to swizzled per-wave LDS
#pragma unroll
      for (int n = 0; n < 4; n++)
#pragma unroll
        for (int i = 0; i < 4; i++) {
          float pv = exp2_fast(sc[m][n][i] - mR[m][i]);
          int r = lg * 4 + i;
          int cbyte = (n * 32 + lr * 2) ^ ((r & 7) << 4);
          *(bf16_t*)(&plds[w][r * 128 + cbyte]) = (bf16_t)pv;
        }
      pf[m][0] = *(const bf16x8*)(&plds[w][lr * 128 + ((lg * 16) ^ ((lr & 7) << 4))]);
      pf[m][1] = *(const bf16x8*)(&plds[w][lr * 128 + ((64 + lg * 16) ^ ((lr & 7) << 4))]);
    }

    // PV + row-sum: V frag loaded once, shared across both m; ones-col = lR
    __builtin_amdgcn_s_setprio(1);
#pragma unroll
    for (int n = 0; n < 8; n++) {
#pragma unroll
      for (int kk = 0; kk < 2; kk++) {
        int r = n * 16 + lr;
        int cb = (kk * 64 + lg * 16) ^ ((r & 7) << 4);
        bf16x8 vf = *(const bf16x8*)(Vb + (((r << 7) + cb) >> 1));
        o[0][n] = MFMA(pf[0][kk], vf, o[0][n]);
        o[1][n] = MFMA(pf[1][kk], vf, o[1][n]);
      }
    }
    o[0][8] = MFMA(pf[0][0], ones, o[0][8]);
    o[0][8] = MFMA(pf[0][1], ones, o[0][8]);
    o[1][8] = MFMA(pf[1][0], ones, o[1][8]);
    o[1][8] = MFMA(pf[1][1], ones, o[1][8]);
    __builtin_amdgcn_s_setprio(0);
    __syncthreads();
    buf ^= 1;
  }

#pragma unroll
  for (int m = 0; m < 2; m++)
#pragma unroll
    for (int i = 0; i < 4; i++) {
      float inv = 1.0f / o[m][8][i];
      int srow = qb * 128 + w * 32 + m * 16 + lg * 4 + i;
#pragma unroll
      for (int n = 0; n < 8; n++) {
        int d = n * 16 + lr;
        ctx[((size_t)(b * S_ + srow)) * D_ + h * HD_ + d] = (bf16_t)(o[m][n][i] * inv);
      }
    }
}

// ---------------- launch ----------------
extern "C" void kernel_launch(void* const* d_in, const int* in_sizes, int n_in,
                              void* d_out, int out_size, void* d_ws, size_t ws_size,
                              hipStream_t stream) {
  const float* x    = (const float*)d_in[0];
  const float* wq   = (const float*)d_in[1];
  const float* wk   = (const float*)d_in[2];
  const float* wv   = (const float*)d_in[3];
  const float* wo   = (const float*)d_in[4];
  const float* fcos = (const float*)d_in[5];
  const float* fsin = (const float*)d_in[6];
  float* out = (float*)d_out;

  // workspace layout (aliased; 160 MB total)
  const size_t SZ_XB    = (size_t)BS_ * D_ * 2;      // 32 MB  (xb, later qrope)
  const size_t SZ_WQKVT = (size_t)NQK_ * D_ * 2;     // 48 MB  (wqkvt, later krope+vtr)
  const size_t SZ_WOT   = (size_t)D_ * D_ * 2;       // 32 MB
  char* p = (char*)d_ws;
  bf16_t* xb    = (bf16_t*)p;                        // then qrope
  bf16_t* wqkvt = (bf16_t*)(p + SZ_XB);              // then krope, vtr
  bf16_t* wot   = (bf16_t*)(p + SZ_XB + SZ_WQKVT);
  bf16_t* qkv   = (bf16_t*)(p + SZ_XB + SZ_WQKVT + SZ_WOT);  // then ctx
  bf16_t* qrope = xb;
  bf16_t* krope = wqkvt;
  bf16_t* vtr   = wqkvt + (size_t)BS_ * NKV_ * HD_;
  bf16_t* ctx   = qkv;

  // Q pre-scale: log2(e) / sqrt(HD)  (scores land in log2 domain)
  const float QSCALE = (float)(0.08838834764831845 * 1.4426950408889634);

  dim3 tb(32, 8);
  // 1. x -> bf16
  k_cvt<<<BS_ * D_ / 1024, 256, 0, stream>>>((const float4*)x, (bf16x4*)xb, BS_ * D_ / 4);
  // 2. transpose+convert weights (fused qkv weight, then wo)
  k_transpose_cvt<<<dim3(D_ / 32, D_ / 32), tb, 0, stream>>>(wq, wqkvt, D_, D_);
  k_transpose_cvt<<<dim3(32, D_ / 32), tb, 0, stream>>>(wk, wqkvt + (size_t)D_ * D_, D_, NKV_ * HD_);
  k_transpose_cvt<<<dim3(32, D_ / 32), tb, 0, stream>>>(wv, wqkvt + (size_t)(D_ + NKV_ * HD_) * D_, D_, NKV_ * HD_);
  k_transpose_cvt<<<dim3(D_ / 32, D_ / 32), tb, 0, stream>>>(wo, wot, D_, D_);
  // 3. fused QKV projection: 256x192 tiles -> grid 16x32 = 512 = 2 clean rounds
  k_gemm8p<bf16_t, 3><<<dim3(BS_ / 256, NQK_ / 192), 512, 0, stream>>>(xb, wqkvt, qkv, BS_, NQK_, D_);
  // 4. RoPE + reorder (Q pre-scaled into log2 domain), V transpose
  k_rope<<<BS_ * NH_ * 64 / 256, 256, 0, stream>>>(qkv, fcos, fsin, qrope, NH_, 0, QSCALE);
  k_rope<<<BS_ * NKV_ * 64 / 256, 256, 0, stream>>>(qkv, fcos, fsin, krope, NKV_, D_, 1.0f);
  k_vtrans<<<dim3(S_ / 32, HD_ / 32, B_ * NKV_), tb, 0, stream>>>(qkv, vtr);
  // 5. flash attention
  k_flash<<<dim3(S_ / 128, NH_, B_), 256, 0, stream>>>(qrope, krope, vtr, ctx);
  // 6. output projection -> f32 out: 256x256 tiles, grid 16x16 = 256 = 1 round
  k_gemm8p<float, 4><<<dim3(BS_ / 256, D_ / 256), 512, 0, stream>>>(ctx, wot, out, BS_, D_, D_);
}